// Round 1
// baseline (661.245 us; speedup 1.0000x reference)
//
#include <hip/hip_runtime.h>
#include <math.h>

typedef unsigned short u16;
typedef unsigned int u32;
typedef __attribute__((ext_vector_type(8))) short short8;
typedef __attribute__((ext_vector_type(4))) float f32x4;

#define B_ 32
#define S_ 512
#define DM_ 512
#define H_ 8
#define NM_ 4

__device__ inline u16 f2b(float f) {
  u32 u = __builtin_bit_cast(u32, f);
  u32 r = u + 0x7fffu + ((u >> 16) & 1u);
  return (u16)(r >> 16);
}
__device__ inline float b2f(u16 b) {
  return __builtin_bit_cast(float, (u32)b << 16);
}
__device__ inline u32 pk2(float a, float b) {
  return (u32)f2b(a) | ((u32)f2b(b) << 16);
}
__device__ inline float eluf(float x) { return x > 0.f ? x : expf(x) - 1.f; }

__device__ inline f32x4 mfma16(short8 a, short8 b, f32x4 c) {
  return __builtin_amdgcn_mfma_f32_16x16x32_bf16(a, b, c, 0, 0, 0);
}
__device__ inline void gload16(const u16* g, u16* l) {
  __builtin_amdgcn_global_load_lds((__attribute__((address_space(1))) void*)(g),
                                   (__attribute__((address_space(3))) void*)(l),
                                   16, 0, 0);
}

// ---------------------------------------------------------------------------
// prep: A_pe[s][d] = PE[s][d] + emb_b[d]  (bf16)   and pb_bias[12][512] gather
// ---------------------------------------------------------------------------
__global__ __launch_bounds__(256) void prep_pe(
    const float* __restrict__ emb_b, const float* __restrict__ bq,
    const float* __restrict__ bk, const float* __restrict__ bv,
    u16* __restrict__ A_pe, float* __restrict__ pb_bias) {
  int bid = blockIdx.x, t = threadIdx.x;
  if (bid < 512) {
    int s = bid;
    float div = expf((2.f * t) * (-9.210340371976184f / 512.f));
    float arg = (float)s * div;
    A_pe[s * 512 + 2 * t] = f2b(sinf(arg) + emb_b[2 * t]);
    A_pe[s * 512 + 2 * t + 1] = f2b(cosf(arg) + emb_b[2 * t + 1]);
  } else {
    int i = (bid - 512) * 256 + t;  // 0..6143
    int z = i >> 9, e = i & 511;
    int ty = z >> 2, m = z & 3;
    const float* bp = (ty == 0) ? bq : (ty == 1) ? bk : bv;
    pb_bias[i] = bp[m * 512 + e];
  }
}

// ---------------------------------------------------------------------------
// transpose all 16 weight matrices (fp32 DMxDM, row d, col e) -> bf16 [e][d]
// ---------------------------------------------------------------------------
__global__ __launch_bounds__(256) void transw(
    const float* __restrict__ Wq, const float* __restrict__ Wk,
    const float* __restrict__ Wv, const float* __restrict__ Wo,
    u16* __restrict__ WTqkv, u16* __restrict__ WTo) {
  __shared__ float tile[64][65];
  int mid = blockIdx.x;
  const float* W;
  u16* WT;
  if (mid < 12) {
    W = ((mid < 4) ? Wq : (mid < 8) ? Wk : Wv) + (long)(mid & 3) * 262144;
    WT = WTqkv + (long)mid * 262144;
  } else {
    W = Wo + (long)(mid - 12) * 262144;
    WT = WTo + (long)(mid - 12) * 262144;
  }
  int d0 = blockIdx.y * 64, e0 = blockIdx.z * 64;
  int t = threadIdx.x;
  int dr = t >> 2, ec = (t & 3) * 16;
#pragma unroll
  for (int j = 0; j < 16; j += 4) {
    float4 v = *(const float4*)&W[(long)(d0 + dr) * 512 + e0 + ec + j];
    tile[dr][ec + j] = v.x;
    tile[dr][ec + j + 1] = v.y;
    tile[dr][ec + j + 2] = v.z;
    tile[dr][ec + j + 3] = v.w;
  }
  __syncthreads();
  int er = t >> 2, dc = (t & 3) * 16;
  u16 tmp[16] __attribute__((aligned(16)));
#pragma unroll
  for (int j = 0; j < 16; ++j) tmp[j] = f2b(tile[dc + j][er]);
  *(short8*)&WT[(long)(e0 + er) * 512 + d0 + dc] = *(short8*)&tmp[0];
  *(short8*)&WT[(long)(e0 + er) * 512 + d0 + dc + 8] = *(short8*)&tmp[8];
}

// ---------------------------------------------------------------------------
// EW[z][f][e] = sum_d emb_W[f][d] * W_z[d][e]   (z = ty*4+m, ty in {q,k,v})
// ---------------------------------------------------------------------------
__global__ __launch_bounds__(256) void ew_kernel(
    const float* __restrict__ Wq, const float* __restrict__ Wk,
    const float* __restrict__ Wv, const float* __restrict__ embW,
    float* __restrict__ EW) {
  int z = blockIdx.x >> 2;
  int f = blockIdx.x & 3;
  const float* W = ((z < 4) ? Wq : (z < 8) ? Wk : Wv) + (long)(z & 3) * 262144;
  int t = threadIdx.x;
  float a0 = 0.f, a1 = 0.f;
  for (int d = 0; d < 512; ++d) {
    float e = embW[f * 512 + d];
    a0 += e * W[(long)d * 512 + t];
    a1 += e * W[(long)d * 512 + t + 256];
  }
  EW[((long)z * 4 + f) * 512 + t] = a0;
  EW[((long)z * 4 + f) * 512 + t + 256] = a1;
}

// ---------------------------------------------------------------------------
// generic bf16 GEMM  C[r][c] = sum_k A[r][k] * BT[c][k] + bias[c]
// A: rows contiguous (lda), K = 512 fixed, tile 128x128, BK=32, 4 waves
// ---------------------------------------------------------------------------
template <bool OBF>
__global__ __launch_bounds__(256) void gemm_bt(
    const u16* __restrict__ A, long sAz, int lda, const u16* __restrict__ BT,
    const float* __restrict__ bias, void* __restrict__ out, long sOz, int ldo) {
  __shared__ u16 As[128 * 32];
  __shared__ u16 Bs[128 * 32];
  const int z = blockIdx.z;
  const int tid = threadIdx.x, w = tid >> 6, l = tid & 63;
  const long row0 = (long)blockIdx.y * 128;
  const u16* Ab = A + (long)z * sAz + row0 * lda;
  const u16* Bb = BT + (long)z * 262144 + (long)blockIdx.x * 128 * 512;
  const u16* ga = Ab + (long)(w * 32 + (l >> 2)) * lda + (l & 3) * 8;
  const u16* gb = Bb + (long)(w * 32 + (l >> 2)) * 512 + (l & 3) * 8;
  u16* lA = As + w * 32 * 32;
  u16* lB = Bs + w * 32 * 32;
  f32x4 acc[4][4] = {};
  const int wr = (w >> 1) * 64, wc = (w & 1) * 64;
  for (int kt = 0; kt < 16; ++kt) {
    gload16(ga + kt * 32, lA);
    gload16(ga + kt * 32 + 16 * lda, lA + 16 * 32);
    gload16(gb + kt * 32, lB);
    gload16(gb + kt * 32 + 16 * 512, lB + 16 * 32);
    __syncthreads();
    short8 af[4], bf[4];
#pragma unroll
    for (int i = 0; i < 4; ++i)
      af[i] = *(const short8*)&As[(wr + i * 16 + (l & 15)) * 32 + (l >> 4) * 8];
#pragma unroll
    for (int i = 0; i < 4; ++i)
      bf[i] = *(const short8*)&Bs[(wc + i * 16 + (l & 15)) * 32 + (l >> 4) * 8];
#pragma unroll
    for (int i = 0; i < 4; ++i)
#pragma unroll
      for (int j = 0; j < 4; ++j) acc[i][j] = mfma16(af[i], bf[j], acc[i][j]);
    __syncthreads();
  }
  const int colB = blockIdx.x * 128 + wc;
#pragma unroll
  for (int i = 0; i < 4; ++i)
#pragma unroll
    for (int j = 0; j < 4; ++j) {
      int col = colB + j * 16 + (l & 15);
      float bb = bias[(long)z * 512 + col];
#pragma unroll
      for (int q = 0; q < 4; ++q) {
        long r = row0 + wr + i * 16 + (l >> 4) * 4 + q;
        float v = acc[i][j][q] + bb;
        if (OBF)
          ((u16*)out)[(long)z * sOz + r * ldo + col] = f2b(v);
        else
          ((float*)out)[(long)z * sOz + r * ldo + col] = v;
      }
    }
}

// ---------------------------------------------------------------------------
// QKV generation for module m: rank-4 update + PB table, fused L2 norm (Q,K)
// Q/K/V row = b*512+s, 512 cols; one block per row, thread t -> e = 2t,2t+1
// ---------------------------------------------------------------------------
__global__ __launch_bounds__(256) void qkv_gen(
    const float* __restrict__ x, const float* __restrict__ EW,
    const float* __restrict__ PB, u16* __restrict__ Qm, u16* __restrict__ Km,
    u16* __restrict__ Vm, int m) {
  const int rid = blockIdx.x;  // b*512+s
  const int s = rid & 511;
  const int t = threadIdx.x;
  const float* xr = x + (long)rid * 7;
  const float xd = xr[3 + m], x0 = xr[0], x1 = xr[1], x2 = xr[2];
  float2 res[3];
#pragma unroll
  for (int ty = 0; ty < 3; ++ty) {
    int z = ty * 4 + m;
    const float* ew = EW + (long)z * 4 * 512;
    float2 e0 = *(const float2*)&ew[0 * 512 + 2 * t];
    float2 e1 = *(const float2*)&ew[1 * 512 + 2 * t];
    float2 e2 = *(const float2*)&ew[2 * 512 + 2 * t];
    float2 e3 = *(const float2*)&ew[3 * 512 + 2 * t];
    float2 pb = *(const float2*)&PB[((long)z * 512 + s) * 512 + 2 * t];
    res[ty].x = xd * e0.x + x0 * e1.x + x1 * e2.x + x2 * e3.x + pb.x;
    res[ty].y = xd * e0.y + x0 * e1.y + x1 * e2.y + x2 * e3.y + pb.y;
  }
  const long obase = (long)rid * 512 + 2 * t;
  *(u32*)&Vm[obase] = pk2(res[2].x, res[2].y);
#pragma unroll
  for (int ty = 0; ty < 2; ++ty) {
    float ss = res[ty].x * res[ty].x + res[ty].y * res[ty].y;
    for (int o = 1; o < 32; o <<= 1) ss += __shfl_xor(ss, o);
    float sc = 1.f / fmaxf(sqrtf(ss), 1e-12f);
    u16* P = ty ? Km : Qm;
    *(u32*)&P[obase] = pk2(res[ty].x * sc, res[ty].y * sc);
  }
}

// ---------------------------------------------------------------------------
// V transpose per module: VT[(b*8+h)*64 + dk][s] = V[(b*512+s)][h*64+dk]
// ---------------------------------------------------------------------------
__global__ __launch_bounds__(256) void vtrans(const u16* __restrict__ V,
                                              u16* __restrict__ VT) {
  __shared__ u16 tile[64][72];
  int bh = blockIdx.x;
  int b = bh >> 3, h = bh & 7;
  int st = blockIdx.y;
  int t = threadIdx.x;
  int sr = t >> 2, kc = (t & 3) * 16;
  long gsrc = ((long)b * 512 + st * 64 + sr) * 512 + h * 64 + kc;
  *(short8*)&tile[sr][kc] = *(const short8*)&V[gsrc];
  *(short8*)&tile[sr][kc + 8] = *(const short8*)&V[gsrc + 8];
  __syncthreads();
  int kr = t >> 2, sc = (t & 3) * 16;
  u16 tmp[16] __attribute__((aligned(16)));
#pragma unroll
  for (int j = 0; j < 16; ++j) tmp[j] = tile[sc + j][kr];
  long gdst = ((long)bh * 64 + kr) * 512 + st * 64 + sc;
  *(short8*)&VT[gdst] = *(short8*)&tmp[0];
  *(short8*)&VT[gdst + 8] = *(short8*)&tmp[8];
}

// ---------------------------------------------------------------------------
// flash attention per module: block = (b*8+h, qb of 128 rows), 4 waves
// wave handles 32 q-rows; KV tiles of 64; online softmax; out -> ctx (b,s,DM)
// ---------------------------------------------------------------------------
__global__ __launch_bounds__(256) void attn_kernel(
    const u16* __restrict__ Q, const u16* __restrict__ K,
    const u16* __restrict__ VT, u16* __restrict__ ctx) {
  __shared__ u16 Qs[128][72];
  __shared__ u16 Ks[64][72];
  __shared__ u16 Vts[64][72];
  __shared__ u16 Ps[4][32][72];
  const int bh = blockIdx.x;  // b*8+h
  const int qb = blockIdx.y;
  const int b = bh >> 3, h = bh & 7;
  const int tid = threadIdx.x, w = tid >> 6, l = tid & 63;
  const long rowbase = (long)b * 512;
  const int hoff = h * 64;

#pragma unroll
  for (int t = 0; t < 4; ++t) {
    int c = tid + t * 256;
    int r = c >> 3, cc = c & 7;
    *(short8*)&Qs[r][cc * 8] =
        *(const short8*)&Q[(rowbase + qb * 128 + r) * 512 + hoff + cc * 8];
  }
  __syncthreads();
  short8 qf[2][2];
#pragma unroll
  for (int rt = 0; rt < 2; ++rt)
#pragma unroll
    for (int kk = 0; kk < 2; ++kk)
      qf[rt][kk] =
          *(const short8*)&Qs[w * 32 + rt * 16 + (l & 15)][kk * 32 + (l >> 4) * 8];

  float m_run[2][4], l_run[2][4];
  f32x4 o_acc[2][4] = {};
#pragma unroll
  for (int rt = 0; rt < 2; ++rt)
#pragma unroll
    for (int q = 0; q < 4; ++q) {
      m_run[rt][q] = -1e30f;
      l_run[rt][q] = 0.f;
    }

  for (int kt = 0; kt < 8; ++kt) {
    __syncthreads();
#pragma unroll
    for (int t = 0; t < 2; ++t) {
      int c = tid + t * 256;
      int tr = c >> 3, cc = c & 7;
      *(short8*)&Ks[tr][cc * 8] =
          *(const short8*)&K[(rowbase + kt * 64 + tr) * 512 + hoff + cc * 8];
      *(short8*)&Vts[tr][cc * 8] =
          *(const short8*)&VT[((long)bh * 64 + tr) * 512 + kt * 64 + cc * 8];
    }
    __syncthreads();
    f32x4 s_acc[2][4] = {};
#pragma unroll
    for (int kk = 0; kk < 2; ++kk) {
      short8 bfr[4];
#pragma unroll
      for (int nt = 0; nt < 4; ++nt)
        bfr[nt] = *(const short8*)&Ks[nt * 16 + (l & 15)][kk * 32 + (l >> 4) * 8];
#pragma unroll
      for (int rt = 0; rt < 2; ++rt)
#pragma unroll
        for (int nt = 0; nt < 4; ++nt)
          s_acc[rt][nt] = mfma16(qf[rt][kk], bfr[nt], s_acc[rt][nt]);
    }
#pragma unroll
    for (int rt = 0; rt < 2; ++rt) {
#pragma unroll
      for (int q = 0; q < 4; ++q) {
        float mx = fmaxf(fmaxf(s_acc[rt][0][q], s_acc[rt][1][q]),
                         fmaxf(s_acc[rt][2][q], s_acc[rt][3][q]));
        for (int o = 1; o < 16; o <<= 1) mx = fmaxf(mx, __shfl_xor(mx, o));
        float mn = fmaxf(m_run[rt][q], mx);
        float alpha = __expf(m_run[rt][q] - mn);
        m_run[rt][q] = mn;
        float rs = 0.f;
#pragma unroll
        for (int nt = 0; nt < 4; ++nt) {
          float p = __expf(s_acc[rt][nt][q] - mn);
          s_acc[rt][nt][q] = p;
          rs += p;
        }
        for (int o = 1; o < 16; o <<= 1) rs += __shfl_xor(rs, o);
        l_run[rt][q] = l_run[rt][q] * alpha + rs;
#pragma unroll
        for (int dt = 0; dt < 4; ++dt) o_acc[rt][dt][q] *= alpha;
      }
#pragma unroll
      for (int nt = 0; nt < 4; ++nt)
#pragma unroll
        for (int q = 0; q < 4; ++q)
          Ps[w][rt * 16 + (l >> 4) * 4 + q][nt * 16 + (l & 15)] =
              f2b(s_acc[rt][nt][q]);
    }
    __syncthreads();
#pragma unroll
    for (int kk = 0; kk < 2; ++kk) {
      short8 pa[2], vb[4];
#pragma unroll
      for (int rt = 0; rt < 2; ++rt)
        pa[rt] =
            *(const short8*)&Ps[w][rt * 16 + (l & 15)][kk * 32 + (l >> 4) * 8];
#pragma unroll
      for (int dt = 0; dt < 4; ++dt)
        vb[dt] =
            *(const short8*)&Vts[dt * 16 + (l & 15)][kk * 32 + (l >> 4) * 8];
#pragma unroll
      for (int rt = 0; rt < 2; ++rt)
#pragma unroll
        for (int dt = 0; dt < 4; ++dt)
          o_acc[rt][dt] = mfma16(pa[rt], vb[dt], o_acc[rt][dt]);
    }
  }
#pragma unroll
  for (int rt = 0; rt < 2; ++rt)
#pragma unroll
    for (int q = 0; q < 4; ++q) {
      float inv = 1.f / l_run[rt][q];
      int r = qb * 128 + w * 32 + rt * 16 + (l >> 4) * 4 + q;
#pragma unroll
      for (int dt = 0; dt < 4; ++dt)
        ctx[(rowbase + r) * 512 + hoff + dt * 16 + (l & 15)] =
            f2b(o_acc[rt][dt][q] * inv);
    }
}

// ---------------------------------------------------------------------------
// conv1: wave per (b,s); 5 output channels; reads combined (b,s,2048) bf16
// ---------------------------------------------------------------------------
__global__ __launch_bounds__(256) void conv1_kernel(
    const u16* __restrict__ combined, const float* __restrict__ w1,
    const float* __restrict__ b1, float* __restrict__ c1) {
  int wid = blockIdx.x * 4 + (threadIdx.x >> 6);
  int l = threadIdx.x & 63;
  int b = wid >> 9, s = wid & 511;
  const u16* row0 = combined + ((long)b * 512 + s) * 2048;
  const u16* rowm = (s > 0) ? row0 - 2048 : nullptr;
  const u16* rowp = (s < 511) ? row0 + 2048 : nullptr;
  float acc[5] = {};
  for (int i = 0; i < 32; ++i) {
    int ic = i * 64 + l;
    float v0 = rowm ? b2f(rowm[ic]) : 0.f;
    float v1 = b2f(row0[ic]);
    float v2 = rowp ? b2f(rowp[ic]) : 0.f;
#pragma unroll
    for (int o = 0; o < 5; ++o) {
      const float* wp = w1 + ((long)o * 2048 + ic) * 3;
      acc[o] = fmaf(v0, wp[0], fmaf(v1, wp[1], fmaf(v2, wp[2], acc[o])));
    }
  }
#pragma unroll
  for (int o = 0; o < 5; ++o) {
    float a = acc[o];
    for (int off = 1; off < 64; off <<= 1) a += __shfl_xor(a, off);
    if (l == 0) {
      a += b1[o];
      c1[((long)b * 5 + o) * 512 + s] = eluf(a);
    }
  }
}

// ---------------------------------------------------------------------------
// conv2 + elu + pairwise max-pool -> flat (32 x 512)
// ---------------------------------------------------------------------------
__global__ __launch_bounds__(256) void conv2pool(const float* __restrict__ c1,
                                                 const float* __restrict__ w2,
                                                 const float* __restrict__ b2,
                                                 float* __restrict__ flat) {
  int idx = blockIdx.x * 256 + threadIdx.x;  // 0..16383
  int b = idx >> 9, r = idx & 511, o = r >> 8, sp = r & 255;
  float mx = -1e30f;
#pragma unroll
  for (int sd = 0; sd < 2; ++sd) {
    int s = sp * 2 + sd;
    float a = b2[o];
#pragma unroll
    for (int ic = 0; ic < 5; ++ic)
#pragma unroll
      for (int k = 0; k < 3; ++k) {
        int ss = s + k - 1;
        if (ss >= 0 && ss < 512)
          a += c1[((long)b * 5 + ic) * 512 + ss] * w2[(o * 5 + ic) * 3 + k];
      }
    mx = fmaxf(mx, eluf(a));
  }
  flat[idx] = mx;
}

// ---------------------------------------------------------------------------
// FC head + LayerNorm, one block per batch element
// ---------------------------------------------------------------------------
__global__ __launch_bounds__(256) void head_kernel(
    const float* __restrict__ flat, const float* __restrict__ w1,
    const float* __restrict__ b1, const float* __restrict__ w2,
    const float* __restrict__ b2, const float* __restrict__ w3,
    const float* __restrict__ b3, const float* __restrict__ g,
    const float* __restrict__ be, float* __restrict__ out) {
  __shared__ float xb[512], z1[256], z2[128], z3[96];
  int b = blockIdx.x, t = threadIdx.x;
  xb[t] = flat[b * 512 + t];
  xb[t + 256] = flat[b * 512 + t + 256];
  __syncthreads();
  {
    float a = b1[t];
    for (int i = 0; i < 512; ++i) a += xb[i] * w1[i * 256 + t];
    z1[t] = eluf(a);
  }
  __syncthreads();
  if (t < 128) {
    float a = b2[t];
    for (int i = 0; i < 256; ++i) a += z1[i] * w2[i * 128 + t];
    z2[t] = eluf(a);
  }
  __syncthreads();
  if (t < 96) {
    float a = b3[t];
    for (int i = 0; i < 128; ++i) a += z2[i] * w3[i * 96 + t];
    z3[t] = a;
  }
  __syncthreads();
  if (t < 96) {
    float mu = 0.f;
    for (int j = 0; j < 96; ++j) mu += z3[j];
    mu *= (1.f / 96.f);
    float sq = 0.f;
    for (int j = 0; j < 96; ++j) {
      float d = z3[j] - mu;
      sq += d * d;
    }
    float var = sq * (1.f / 96.f);
    out[b * 96 + t] = (z3[t] - mu) / sqrtf(var + 1e-5f) * g[t] + be[t];
  }
}

// ---------------------------------------------------------------------------
extern "C" void kernel_launch(void* const* d_in, const int* in_sizes, int n_in,
                              void* d_out, int out_size, void* d_ws,
                              size_t ws_size, hipStream_t stream) {
  (void)in_sizes; (void)n_in; (void)out_size;
  const float* x    = (const float*)d_in[0];
  const float* embW = (const float*)d_in[1];
  const float* embB = (const float*)d_in[2];
  const float* Wq   = (const float*)d_in[3];
  const float* bq   = (const float*)d_in[4];
  const float* Wk   = (const float*)d_in[5];
  const float* bk   = (const float*)d_in[6];
  const float* Wv   = (const float*)d_in[7];
  const float* bv   = (const float*)d_in[8];
  const float* Wo   = (const float*)d_in[9];
  const float* bo   = (const float*)d_in[10];
  const float* c1w  = (const float*)d_in[11];
  const float* c1b  = (const float*)d_in[12];
  const float* c2w  = (const float*)d_in[13];
  const float* c2b  = (const float*)d_in[14];
  const float* f1w  = (const float*)d_in[15];
  const float* f1b  = (const float*)d_in[16];
  const float* f2w  = (const float*)d_in[17];
  const float* f2b_ = (const float*)d_in[18];
  const float* f3w  = (const float*)d_in[19];
  const float* f3b  = (const float*)d_in[20];
  const float* lng  = (const float*)d_in[21];
  const float* lnb  = (const float*)d_in[22];
  float* out = (float*)d_out;

  char* p = (char*)d_ws;
  const size_t NEED = 173006848;
  if (ws_size < NEED) return;  // workspace too small; fail loudly via mismatch
  u16*   A_pe    = (u16*)(p + 0);
  u16*   WTqkv   = (u16*)(p + 524288);
  u16*   WTo     = (u16*)(p + 6815744);
  float* pb_bias = (float*)(p + 8912896);
  float* EW      = (float*)(p + 8937472);
  float* PB      = (float*)(p + 9035776);
  u16*   Qm      = (u16*)(p + 21618688);
  u16*   Km      = (u16*)(p + 38395904);
  u16*   Vm      = (u16*)(p + 55173120);
  u16*   ctxm    = (u16*)(p + 71950336);
  u16*   VTm     = (u16*)(p + 88727552);
  u16*   combined= (u16*)(p + 105504768);
  float* c1buf   = (float*)(p + 172613632);
  float* flat    = (float*)(p + 172941312);

  prep_pe<<<536, 256, 0, stream>>>(embB, bq, bk, bv, A_pe, pb_bias);
  transw<<<dim3(16, 8, 8), 256, 0, stream>>>(Wq, Wk, Wv, Wo, WTqkv, WTo);
  ew_kernel<<<48, 256, 0, stream>>>(Wq, Wk, Wv, embW, EW);
  // PB[z] = (PE+emb_b) @ W_z + bias_z   (z = ty*4+m, fp32 out)
  gemm_bt<false><<<dim3(4, 4, 12), 256, 0, stream>>>(
      A_pe, 0, 512, WTqkv, pb_bias, (void*)PB, 262144, 512);

  for (int m = 0; m < 4; ++m) {
    qkv_gen<<<16384, 256, 0, stream>>>(x, EW, PB, Qm, Km, Vm, m);
    vtrans<<<dim3(256, 8), 256, 0, stream>>>(Vm, VTm);
    attn_kernel<<<dim3(256, 4), 256, 0, stream>>>(Qm, Km, VTm, ctxm);
    // O-projection: ctx_m (16384x512) @ Wo_m^T -> combined[:, m*512 : ...]
    gemm_bt<true><<<dim3(4, 128, 1), 256, 0, stream>>>(
        ctxm, 0, 512, WTo + (long)m * 262144, bo + m * 512,
        (void*)(combined + m * 512), 0, 2048);
  }

  conv1_kernel<<<4096, 256, 0, stream>>>(combined, c1w, c1b, c1buf);
  conv2pool<<<64, 256, 0, stream>>>(c1buf, c2w, c2b, flat);
  head_kernel<<<32, 256, 0, stream>>>(flat, f1w, f1b, f2w, f2b_, f3w, f3b,
                                      lng, lnb, out);
}

// Round 2
// 530.961 us; speedup vs baseline: 1.2454x; 1.2454x over previous
//
#include <hip/hip_runtime.h>
#include <math.h>

typedef unsigned short u16;
typedef unsigned int u32;
typedef __attribute__((ext_vector_type(8))) short short8;
typedef __attribute__((ext_vector_type(4))) float f32x4;

__device__ inline u16 f2b(float f) {
  u32 u = __builtin_bit_cast(u32, f);
  u32 r = u + 0x7fffu + ((u >> 16) & 1u);
  return (u16)(r >> 16);
}
__device__ inline float b2f(u16 b) {
  return __builtin_bit_cast(float, (u32)b << 16);
}
__device__ inline u32 pk2(float a, float b) {
  return (u32)f2b(a) | ((u32)f2b(b) << 16);
}
__device__ inline float eluf(float x) { return x > 0.f ? x : expf(x) - 1.f; }

__device__ inline f32x4 mfma16(short8 a, short8 b, f32x4 c) {
  return __builtin_amdgcn_mfma_f32_16x16x32_bf16(a, b, c, 0, 0, 0);
}
__device__ inline void gload16(const u16* g, u16* l) {
  __builtin_amdgcn_global_load_lds((__attribute__((address_space(1))) void*)(g),
                                   (__attribute__((address_space(3))) void*)(l),
                                   16, 0, 0);
}

// ---------------------------------------------------------------------------
// prep: A_pe[s][d] = PE[s][d] + emb_b[d]  (bf16)   and pb_bias[12][512] gather
// ---------------------------------------------------------------------------
__global__ __launch_bounds__(256) void prep_pe(
    const float* __restrict__ emb_b, const float* __restrict__ bq,
    const float* __restrict__ bk, const float* __restrict__ bv,
    u16* __restrict__ A_pe, float* __restrict__ pb_bias) {
  int bid = blockIdx.x, t = threadIdx.x;
  if (bid < 512) {
    int s = bid;
    float div = expf((2.f * t) * (-9.210340371976184f / 512.f));
    float arg = (float)s * div;
    A_pe[s * 512 + 2 * t] = f2b(sinf(arg) + emb_b[2 * t]);
    A_pe[s * 512 + 2 * t + 1] = f2b(cosf(arg) + emb_b[2 * t + 1]);
  } else {
    int i = (bid - 512) * 256 + t;  // 0..6143
    int z = i >> 9, e = i & 511;
    int ty = z >> 2, m = z & 3;
    const float* bp = (ty == 0) ? bq : (ty == 1) ? bk : bv;
    pb_bias[i] = bp[m * 512 + e];
  }
}

// ---------------------------------------------------------------------------
// transpose the 12 QKV weight matrices (fp32 DMxDM, row d, col e) -> bf16 [e][d]
// ---------------------------------------------------------------------------
__global__ __launch_bounds__(256) void transw(
    const float* __restrict__ Wq, const float* __restrict__ Wk,
    const float* __restrict__ Wv, u16* __restrict__ WTqkv) {
  __shared__ float tile[64][65];
  int mid = blockIdx.x;
  const float* W = ((mid < 4) ? Wq : (mid < 8) ? Wk : Wv) + (long)(mid & 3) * 262144;
  u16* WT = WTqkv + (long)mid * 262144;
  int d0 = blockIdx.y * 64, e0 = blockIdx.z * 64;
  int t = threadIdx.x;
  int dr = t >> 2, ec = (t & 3) * 16;
#pragma unroll
  for (int j = 0; j < 16; j += 4) {
    float4 v = *(const float4*)&W[(long)(d0 + dr) * 512 + e0 + ec + j];
    tile[dr][ec + j] = v.x;
    tile[dr][ec + j + 1] = v.y;
    tile[dr][ec + j + 2] = v.z;
    tile[dr][ec + j + 3] = v.w;
  }
  __syncthreads();
  int er = t >> 2, dc = (t & 3) * 16;
  u16 tmp[16] __attribute__((aligned(16)));
#pragma unroll
  for (int j = 0; j < 16; ++j) tmp[j] = f2b(tile[dc + j][er]);
  *(short8*)&WT[(long)(e0 + er) * 512 + d0 + dc] = *(short8*)&tmp[0];
  *(short8*)&WT[(long)(e0 + er) * 512 + d0 + dc + 8] = *(short8*)&tmp[8];
}

// ---------------------------------------------------------------------------
// EW[z][f][e] = sum_d emb_W[f][d] * W_z[d][e]   (z = ty*4+m, ty in {q,k,v})
// ---------------------------------------------------------------------------
__global__ __launch_bounds__(256) void ew_kernel(
    const float* __restrict__ Wq, const float* __restrict__ Wk,
    const float* __restrict__ Wv, const float* __restrict__ embW,
    float* __restrict__ EW) {
  int z = blockIdx.x >> 2;
  int f = blockIdx.x & 3;
  const float* W = ((z < 4) ? Wq : (z < 8) ? Wk : Wv) + (long)(z & 3) * 262144;
  int t = threadIdx.x;
  float a0 = 0.f, a1 = 0.f;
  for (int d = 0; d < 512; ++d) {
    float e = embW[f * 512 + d];
    a0 += e * W[(long)d * 512 + t];
    a1 += e * W[(long)d * 512 + t + 256];
  }
  EW[((long)z * 4 + f) * 512 + t] = a0;
  EW[((long)z * 4 + f) * 512 + t + 256] = a1;
}

// ---------------------------------------------------------------------------
// WEFF_m[d][j] = sum_e Wo_m[d][e] * w1[o][m*512+e][k]   (j = o*3+k, 15 + pad)
// stored transposed: WEFFT[m][j][d] bf16.  Extra block computes bias_t.
// ---------------------------------------------------------------------------
__global__ __launch_bounds__(64) void weff_kernel(
    const float* __restrict__ Wo, const float* __restrict__ bo,
    const float* __restrict__ w1, u16* __restrict__ WEFFT,
    float* __restrict__ bias_t) {
  const int bid = blockIdx.x, l = threadIdx.x;
  if (bid < 2048) {
    int m = bid >> 9, d = bid & 511;
    const float* wrow = Wo + ((long)m * 512 + d) * 512;
    float a[15] = {};
#pragma unroll
    for (int i = 0; i < 8; ++i) {
      int e = l * 8 + i;
      float wv = wrow[e];
#pragma unroll
      for (int o = 0; o < 5; ++o)
#pragma unroll
        for (int k = 0; k < 3; ++k)
          a[o * 3 + k] += wv * w1[((long)o * 2048 + m * 512 + e) * 3 + k];
    }
#pragma unroll
    for (int j = 0; j < 15; ++j) {
      float v = a[j];
      for (int o = 1; o < 64; o <<= 1) v += __shfl_xor(v, o);
      if (l == 0) WEFFT[((long)m * 16 + j) * 512 + d] = f2b(v);
    }
    if (l == 0) WEFFT[((long)m * 16 + 15) * 512 + d] = 0;
  } else {
    float a[15] = {};
    for (int c = l; c < 2048; c += 64) {
      float bv = bo[c];
#pragma unroll
      for (int o = 0; o < 5; ++o)
#pragma unroll
        for (int k = 0; k < 3; ++k)
          a[o * 3 + k] += bv * w1[((long)o * 2048 + c) * 3 + k];
    }
#pragma unroll
    for (int j = 0; j < 15; ++j) {
      float v = a[j];
      for (int o = 1; o < 64; o <<= 1) v += __shfl_xor(v, o);
      if (l == 0) bias_t[j] = v;
    }
    if (l == 0) bias_t[15] = 0.f;
  }
}

// ---------------------------------------------------------------------------
// generic bf16 GEMM  C[r][c] = sum_k A[r][k] * BT[c][k] + bias[c]
// A: rows contiguous (lda), K = 512 fixed, tile 128x128, BK=32, 4 waves
// ---------------------------------------------------------------------------
template <bool OBF>
__global__ __launch_bounds__(256) void gemm_bt(
    const u16* __restrict__ A, long sAz, int lda, const u16* __restrict__ BT,
    const float* __restrict__ bias, void* __restrict__ out, long sOz, int ldo) {
  __shared__ u16 As[128 * 32];
  __shared__ u16 Bs[128 * 32];
  const int z = blockIdx.z;
  const int tid = threadIdx.x, w = tid >> 6, l = tid & 63;
  const long row0 = (long)blockIdx.y * 128;
  const u16* Ab = A + (long)z * sAz + row0 * lda;
  const u16* Bb = BT + (long)z * 262144 + (long)blockIdx.x * 128 * 512;
  const u16* ga = Ab + (long)(w * 32 + (l >> 2)) * lda + (l & 3) * 8;
  const u16* gb = Bb + (long)(w * 32 + (l >> 2)) * 512 + (l & 3) * 8;
  u16* lA = As + w * 32 * 32;
  u16* lB = Bs + w * 32 * 32;
  f32x4 acc[4][4] = {};
  const int wr = (w >> 1) * 64, wc = (w & 1) * 64;
  for (int kt = 0; kt < 16; ++kt) {
    gload16(ga + kt * 32, lA);
    gload16(ga + kt * 32 + 16 * lda, lA + 16 * 32);
    gload16(gb + kt * 32, lB);
    gload16(gb + kt * 32 + 16 * 512, lB + 16 * 32);
    __syncthreads();
    short8 af[4], bf[4];
#pragma unroll
    for (int i = 0; i < 4; ++i)
      af[i] = *(const short8*)&As[(wr + i * 16 + (l & 15)) * 32 + (l >> 4) * 8];
#pragma unroll
    for (int i = 0; i < 4; ++i)
      bf[i] = *(const short8*)&Bs[(wc + i * 16 + (l & 15)) * 32 + (l >> 4) * 8];
#pragma unroll
    for (int i = 0; i < 4; ++i)
#pragma unroll
      for (int j = 0; j < 4; ++j) acc[i][j] = mfma16(af[i], bf[j], acc[i][j]);
    __syncthreads();
  }
  const int colB = blockIdx.x * 128 + wc;
#pragma unroll
  for (int i = 0; i < 4; ++i)
#pragma unroll
    for (int j = 0; j < 4; ++j) {
      int col = colB + j * 16 + (l & 15);
      float bb = bias[(long)z * 512 + col];
#pragma unroll
      for (int q = 0; q < 4; ++q) {
        long r = row0 + wr + i * 16 + (l >> 4) * 4 + q;
        float v = acc[i][j][q] + bb;
        if (OBF)
          ((u16*)out)[(long)z * sOz + r * ldo + col] = f2b(v);
        else
          ((float*)out)[(long)z * sOz + r * ldo + col] = v;
      }
    }
}

// ---------------------------------------------------------------------------
// QKV generation for module m: rank-4 update + PB table, fused L2 norm (Q,K)
// ---------------------------------------------------------------------------
__global__ __launch_bounds__(256) void qkv_gen(
    const float* __restrict__ x, const float* __restrict__ EW,
    const float* __restrict__ PB, u16* __restrict__ Qm, u16* __restrict__ Km,
    u16* __restrict__ Vm, int m) {
  const int rid = blockIdx.x;  // b*512+s
  const int s = rid & 511;
  const int t = threadIdx.x;
  const float* xr = x + (long)rid * 7;
  const float xd = xr[3 + m], x0 = xr[0], x1 = xr[1], x2 = xr[2];
  float2 res[3];
#pragma unroll
  for (int ty = 0; ty < 3; ++ty) {
    int z = ty * 4 + m;
    const float* ew = EW + (long)z * 4 * 512;
    float2 e0 = *(const float2*)&ew[0 * 512 + 2 * t];
    float2 e1 = *(const float2*)&ew[1 * 512 + 2 * t];
    float2 e2 = *(const float2*)&ew[2 * 512 + 2 * t];
    float2 e3 = *(const float2*)&ew[3 * 512 + 2 * t];
    float2 pb = *(const float2*)&PB[((long)z * 512 + s) * 512 + 2 * t];
    res[ty].x = xd * e0.x + x0 * e1.x + x1 * e2.x + x2 * e3.x + pb.x;
    res[ty].y = xd * e0.y + x0 * e1.y + x1 * e2.y + x2 * e3.y + pb.y;
  }
  const long obase = (long)rid * 512 + 2 * t;
  *(u32*)&Vm[obase] = pk2(res[2].x, res[2].y);
#pragma unroll
  for (int ty = 0; ty < 2; ++ty) {
    float ss = res[ty].x * res[ty].x + res[ty].y * res[ty].y;
    for (int o = 1; o < 32; o <<= 1) ss += __shfl_xor(ss, o);
    float sc = 1.f / fmaxf(sqrtf(ss), 1e-12f);
    u16* P = ty ? Km : Qm;
    *(u32*)&P[obase] = pk2(res[ty].x * sc, res[ty].y * sc);
  }
}

// ---------------------------------------------------------------------------
// V transpose per module: VT[(b*8+h)*64 + dk][s] = V[(b*512+s)][h*64+dk]
// ---------------------------------------------------------------------------
__global__ __launch_bounds__(256) void vtrans(const u16* __restrict__ V,
                                              u16* __restrict__ VT) {
  __shared__ u16 tile[64][72];
  int bh = blockIdx.x;
  int b = bh >> 3, h = bh & 7;
  int st = blockIdx.y;
  int t = threadIdx.x;
  int sr = t >> 2, kc = (t & 3) * 16;
  long gsrc = ((long)b * 512 + st * 64 + sr) * 512 + h * 64 + kc;
  *(short8*)&tile[sr][kc] = *(const short8*)&V[gsrc];
  *(short8*)&tile[sr][kc + 8] = *(const short8*)&V[gsrc + 8];
  __syncthreads();
  int kr = t >> 2, sc = (t & 3) * 16;
  u16 tmp[16] __attribute__((aligned(16)));
#pragma unroll
  for (int j = 0; j < 16; ++j) tmp[j] = tile[sc + j][kr];
  long gdst = ((long)bh * 64 + kr) * 512 + st * 64 + sc;
  *(short8*)&VT[gdst] = *(short8*)&tmp[0];
  *(short8*)&VT[gdst + 8] = *(short8*)&tmp[8];
}

// ---------------------------------------------------------------------------
// flash attention per module
// ---------------------------------------------------------------------------
__global__ __launch_bounds__(256) void attn_kernel(
    const u16* __restrict__ Q, const u16* __restrict__ K,
    const u16* __restrict__ VT, u16* __restrict__ ctx) {
  __shared__ u16 Qs[128][72];
  __shared__ u16 Ks[64][72];
  __shared__ u16 Vts[64][72];
  __shared__ u16 Ps[4][32][72];
  const int bh = blockIdx.x;  // b*8+h
  const int qb = blockIdx.y;
  const int b = bh >> 3, h = bh & 7;
  const int tid = threadIdx.x, w = tid >> 6, l = tid & 63;
  const long rowbase = (long)b * 512;
  const int hoff = h * 64;

#pragma unroll
  for (int t = 0; t < 4; ++t) {
    int c = tid + t * 256;
    int r = c >> 3, cc = c & 7;
    *(short8*)&Qs[r][cc * 8] =
        *(const short8*)&Q[(rowbase + qb * 128 + r) * 512 + hoff + cc * 8];
  }
  __syncthreads();
  short8 qf[2][2];
#pragma unroll
  for (int rt = 0; rt < 2; ++rt)
#pragma unroll
    for (int kk = 0; kk < 2; ++kk)
      qf[rt][kk] =
          *(const short8*)&Qs[w * 32 + rt * 16 + (l & 15)][kk * 32 + (l >> 4) * 8];

  float m_run[2][4], l_run[2][4];
  f32x4 o_acc[2][4] = {};
#pragma unroll
  for (int rt = 0; rt < 2; ++rt)
#pragma unroll
    for (int q = 0; q < 4; ++q) {
      m_run[rt][q] = -1e30f;
      l_run[rt][q] = 0.f;
    }

  for (int kt = 0; kt < 8; ++kt) {
    __syncthreads();
#pragma unroll
    for (int t = 0; t < 2; ++t) {
      int c = tid + t * 256;
      int tr = c >> 3, cc = c & 7;
      *(short8*)&Ks[tr][cc * 8] =
          *(const short8*)&K[(rowbase + kt * 64 + tr) * 512 + hoff + cc * 8];
      *(short8*)&Vts[tr][cc * 8] =
          *(const short8*)&VT[((long)bh * 64 + tr) * 512 + kt * 64 + cc * 8];
    }
    __syncthreads();
    f32x4 s_acc[2][4] = {};
#pragma unroll
    for (int kk = 0; kk < 2; ++kk) {
      short8 bfr[4];
#pragma unroll
      for (int nt = 0; nt < 4; ++nt)
        bfr[nt] = *(const short8*)&Ks[nt * 16 + (l & 15)][kk * 32 + (l >> 4) * 8];
#pragma unroll
      for (int rt = 0; rt < 2; ++rt)
#pragma unroll
        for (int nt = 0; nt < 4; ++nt)
          s_acc[rt][nt] = mfma16(qf[rt][kk], bfr[nt], s_acc[rt][nt]);
    }
#pragma unroll
    for (int rt = 0; rt < 2; ++rt) {
#pragma unroll
      for (int q = 0; q < 4; ++q) {
        float mx = fmaxf(fmaxf(s_acc[rt][0][q], s_acc[rt][1][q]),
                         fmaxf(s_acc[rt][2][q], s_acc[rt][3][q]));
        for (int o = 1; o < 16; o <<= 1) mx = fmaxf(mx, __shfl_xor(mx, o));
        float mn = fmaxf(m_run[rt][q], mx);
        float alpha = __expf(m_run[rt][q] - mn);
        m_run[rt][q] = mn;
        float rs = 0.f;
#pragma unroll
        for (int nt = 0; nt < 4; ++nt) {
          float p = __expf(s_acc[rt][nt][q] - mn);
          s_acc[rt][nt][q] = p;
          rs += p;
        }
        for (int o = 1; o < 16; o <<= 1) rs += __shfl_xor(rs, o);
        l_run[rt][q] = l_run[rt][q] * alpha + rs;
#pragma unroll
        for (int dt = 0; dt < 4; ++dt) o_acc[rt][dt][q] *= alpha;
      }
#pragma unroll
      for (int nt = 0; nt < 4; ++nt)
#pragma unroll
        for (int q = 0; q < 4; ++q)
          Ps[w][rt * 16 + (l >> 4) * 4 + q][nt * 16 + (l & 15)] =
              f2b(s_acc[rt][nt][q]);
    }
    __syncthreads();
#pragma unroll
    for (int kk = 0; kk < 2; ++kk) {
      short8 pa[2], vb[4];
#pragma unroll
      for (int rt = 0; rt < 2; ++rt)
        pa[rt] =
            *(const short8*)&Ps[w][rt * 16 + (l & 15)][kk * 32 + (l >> 4) * 8];
#pragma unroll
      for (int dt = 0; dt < 4; ++dt)
        vb[dt] =
            *(const short8*)&Vts[dt * 16 + (l & 15)][kk * 32 + (l >> 4) * 8];
#pragma unroll
      for (int rt = 0; rt < 2; ++rt)
#pragma unroll
        for (int dt = 0; dt < 4; ++dt)
          o_acc[rt][dt] = mfma16(pa[rt], vb[dt], o_acc[rt][dt]);
    }
  }
#pragma unroll
  for (int rt = 0; rt < 2; ++rt)
#pragma unroll
    for (int q = 0; q < 4; ++q) {
      float inv = 1.f / l_run[rt][q];
      int r = qb * 128 + w * 32 + rt * 16 + (l >> 4) * 4 + q;
#pragma unroll
      for (int dt = 0; dt < 4; ++dt)
        ctx[(rowbase + r) * 512 + hoff + dt * 16 + (l & 15)] =
            f2b(o_acc[rt][dt][q] * inv);
    }
}

// ---------------------------------------------------------------------------
// t[r][j] = sum_m ctx_m[r][:] . WEFFT[m][j][:]   (r = b*512+s, j = o*3+k)
// one wave per 16 rows; 16x16x32 MFMA; K = 4 x 512
// ---------------------------------------------------------------------------
__global__ __launch_bounds__(64) void t_gemm(const u16* __restrict__ ctx4,
                                             const u16* __restrict__ WEFFT,
                                             float* __restrict__ t) {
  const int l = threadIdx.x;
  const long r0 = (long)blockIdx.x * 16;
  f32x4 acc = {};
#pragma unroll
  for (int m = 0; m < 4; ++m) {
    const u16* A =
        ctx4 + (long)m * 8388608 + (r0 + (l & 15)) * 512 + (l >> 4) * 8;
    const u16* Bb = WEFFT + m * 8192 + (l & 15) * 512 + (l >> 4) * 8;
#pragma unroll
    for (int kt = 0; kt < 16; ++kt) {
      short8 af = *(const short8*)(A + kt * 32);
      short8 bf = *(const short8*)(Bb + kt * 32);
      acc = mfma16(af, bf, acc);
    }
  }
#pragma unroll
  for (int q = 0; q < 4; ++q)
    t[(r0 + (l >> 4) * 4 + q) * 16 + (l & 15)] = acc[q];
}

// ---------------------------------------------------------------------------
// c1[b][o][s] = elu(b1[o] + sum_k in-range (t[b,s+k-1,o*3+k] + bias_t[o*3+k]))
// ---------------------------------------------------------------------------
__global__ __launch_bounds__(256) void c1_kernel(
    const float* __restrict__ t, const float* __restrict__ bias_t,
    const float* __restrict__ b1, float* __restrict__ c1) {
  int idx = blockIdx.x * 256 + threadIdx.x;  // 0..81919  (b*5+o)*512+s
  int s = idx & 511;
  int rest = idx >> 9;
  int o = rest % 5, b = rest / 5;
  float a = b1[o];
  long base = (long)b * 512;
#pragma unroll
  for (int k = 0; k < 3; ++k) {
    int ss = s + k - 1;
    if (ss >= 0 && ss < 512)
      a += t[(base + ss) * 16 + o * 3 + k] + bias_t[o * 3 + k];
  }
  c1[idx] = eluf(a);
}

// ---------------------------------------------------------------------------
// conv2 + elu + pairwise max-pool -> flat (32 x 512)
// ---------------------------------------------------------------------------
__global__ __launch_bounds__(256) void conv2pool(const float* __restrict__ c1,
                                                 const float* __restrict__ w2,
                                                 const float* __restrict__ b2,
                                                 float* __restrict__ flat) {
  int idx = blockIdx.x * 256 + threadIdx.x;  // 0..16383
  int b = idx >> 9, r = idx & 511, o = r >> 8, sp = r & 255;
  float mx = -1e30f;
#pragma unroll
  for (int sd = 0; sd < 2; ++sd) {
    int s = sp * 2 + sd;
    float a = b2[o];
#pragma unroll
    for (int ic = 0; ic < 5; ++ic)
#pragma unroll
      for (int k = 0; k < 3; ++k) {
        int ss = s + k - 1;
        if (ss >= 0 && ss < 512)
          a += c1[((long)b * 5 + ic) * 512 + ss] * w2[(o * 5 + ic) * 3 + k];
      }
    mx = fmaxf(mx, eluf(a));
  }
  flat[idx] = mx;
}

// ---------------------------------------------------------------------------
// FC head + LayerNorm, one block per batch element
// ---------------------------------------------------------------------------
__global__ __launch_bounds__(256) void head_kernel(
    const float* __restrict__ flat, const float* __restrict__ w1,
    const float* __restrict__ b1, const float* __restrict__ w2,
    const float* __restrict__ b2, const float* __restrict__ w3,
    const float* __restrict__ b3, const float* __restrict__ g,
    const float* __restrict__ be, float* __restrict__ out) {
  __shared__ float xb[512], z1[256], z2[128], z3[96];
  int b = blockIdx.x, t = threadIdx.x;
  xb[t] = flat[b * 512 + t];
  xb[t + 256] = flat[b * 512 + t + 256];
  __syncthreads();
  {
    float a = b1[t];
    for (int i = 0; i < 512; ++i) a += xb[i] * w1[i * 256 + t];
    z1[t] = eluf(a);
  }
  __syncthreads();
  if (t < 128) {
    float a = b2[t];
    for (int i = 0; i < 256; ++i) a += z1[i] * w2[i * 128 + t];
    z2[t] = eluf(a);
  }
  __syncthreads();
  if (t < 96) {
    float a = b3[t];
    for (int i = 0; i < 128; ++i) a += z2[i] * w3[i * 96 + t];
    z3[t] = a;
  }
  __syncthreads();
  if (t < 96) {
    float mu = 0.f;
    for (int j = 0; j < 96; ++j) mu += z3[j];
    mu *= (1.f / 96.f);
    float sq = 0.f;
    for (int j = 0; j < 96; ++j) {
      float d = z3[j] - mu;
      sq += d * d;
    }
    float var = sq * (1.f / 96.f);
    out[b * 96 + t] = (z3[t] - mu) / sqrtf(var + 1e-5f) * g[t] + be[t];
  }
}

// ---------------------------------------------------------------------------
extern "C" void kernel_launch(void* const* d_in, const int* in_sizes, int n_in,
                              void* d_out, int out_size, void* d_ws,
                              size_t ws_size, hipStream_t stream) {
  (void)in_sizes; (void)n_in; (void)out_size;
  const float* x    = (const float*)d_in[0];
  const float* embW = (const float*)d_in[1];
  const float* embB = (const float*)d_in[2];
  const float* Wq   = (const float*)d_in[3];
  const float* bq   = (const float*)d_in[4];
  const float* Wk   = (const float*)d_in[5];
  const float* bk   = (const float*)d_in[6];
  const float* Wv   = (const float*)d_in[7];
  const float* bv   = (const float*)d_in[8];
  const float* Wo   = (const float*)d_in[9];
  const float* bo   = (const float*)d_in[10];
  const float* c1w  = (const float*)d_in[11];
  const float* c1b  = (const float*)d_in[12];
  const float* c2w  = (const float*)d_in[13];
  const float* c2b  = (const float*)d_in[14];
  const float* f1w  = (const float*)d_in[15];
  const float* f1b  = (const float*)d_in[16];
  const float* f2w  = (const float*)d_in[17];
  const float* f2b_ = (const float*)d_in[18];
  const float* f3w  = (const float*)d_in[19];
  const float* f3b  = (const float*)d_in[20];
  const float* lng  = (const float*)d_in[21];
  const float* lnb  = (const float*)d_in[22];
  float* out = (float*)d_out;

  char* p = (char*)d_ws;
  const size_t NEED = 155246720;
  if (ws_size < NEED) return;
  u16*   A_pe    = (u16*)(p + 0);          //   512x512 bf16
  u16*   WTqkv   = (u16*)(p + 524288);     //  12x512x512 bf16
  float* pb_bias = (float*)(p + 6815744);  //  12x512 f32
  float* EW      = (float*)(p + 6840320);  //  12x4x512 f32
  float* PB      = (float*)(p + 6938624);  //  12x512x512 f32
  u16*   Qm      = (u16*)(p + 19521536);   //  16384x512 bf16
  u16*   Km      = (u16*)(p + 36298752);
  u16*   Vm      = (u16*)(p + 53075968);
  u16*   VTm     = (u16*)(p + 69853184);
  u16*   ctx4    = (u16*)(p + 86630400);   //  4x16384x512 bf16
  u16*   WEFFT   = (u16*)(p + 153739264);  //  4x16x512 bf16
  float* bias_t  = (float*)(p + 153804800);//  16 f32
  float* t_buf   = (float*)(p + 153804928);//  16384x16 f32
  float* c1buf   = (float*)(p + 154853504);//  32x5x512 f32
  float* flat    = (float*)(p + 155181184);//  32x512 f32

  prep_pe<<<536, 256, 0, stream>>>(embB, bq, bk, bv, A_pe, pb_bias);
  transw<<<dim3(12, 8, 8), 256, 0, stream>>>(Wq, Wk, Wv, WTqkv);
  ew_kernel<<<48, 256, 0, stream>>>(Wq, Wk, Wv, embW, EW);
  weff_kernel<<<2049, 64, 0, stream>>>(Wo, bo, c1w, WEFFT, bias_t);
  // PB[z] = (PE+emb_b) @ W_z + bias_z   (z = ty*4+m, fp32 out)
  gemm_bt<false><<<dim3(4, 4, 12), 256, 0, stream>>>(
      A_pe, 0, 512, WTqkv, pb_bias, (void*)PB, 262144, 512);

  for (int m = 0; m < 4; ++m) {
    qkv_gen<<<16384, 256, 0, stream>>>(x, EW, PB, Qm, Km, Vm, m);
    vtrans<<<dim3(256, 8), 256, 0, stream>>>(Vm, VTm);
    attn_kernel<<<dim3(256, 4), 256, 0, stream>>>(
        Qm, Km, VTm, ctx4 + (long)m * 8388608);
  }

  t_gemm<<<1024, 64, 0, stream>>>(ctx4, WEFFT, t_buf);
  c1_kernel<<<320, 256, 0, stream>>>(t_buf, bias_t, c1b, c1buf);
  conv2pool<<<64, 256, 0, stream>>>(c1buf, c2w, c2b, flat);
  head_kernel<<<32, 256, 0, stream>>>(flat, f1w, f1b, f2w, f2b_, f3w, f3b,
                                      lng, lnb, out);
}

// Round 3
// 451.156 us; speedup vs baseline: 1.4657x; 1.1769x over previous
//
#include <hip/hip_runtime.h>
#include <math.h>

typedef unsigned short u16;
typedef unsigned int u32;
typedef __attribute__((ext_vector_type(8))) short short8;
typedef __attribute__((ext_vector_type(4))) float f32x4;

__device__ inline u16 f2b(float f) {
  u32 u = __builtin_bit_cast(u32, f);
  u32 r = u + 0x7fffu + ((u >> 16) & 1u);
  return (u16)(r >> 16);
}
__device__ inline float b2f(u16 b) {
  return __builtin_bit_cast(float, (u32)b << 16);
}
__device__ inline u32 pk2(float a, float b) {
  return (u32)f2b(a) | ((u32)f2b(b) << 16);
}
__device__ inline float eluf(float x) { return x > 0.f ? x : expf(x) - 1.f; }

__device__ inline f32x4 mfma16(short8 a, short8 b, f32x4 c) {
  return __builtin_amdgcn_mfma_f32_16x16x32_bf16(a, b, c, 0, 0, 0);
}
__device__ inline void gload16(const u16* g, u16* l) {
  __builtin_amdgcn_global_load_lds((__attribute__((address_space(1))) void*)(g),
                                   (__attribute__((address_space(3))) void*)(l),
                                   16, 0, 0);
}

// ---------------------------------------------------------------------------
// prep: A_pe[s][d] = PE[s][d] + emb_b[d]  (bf16)   and pb_bias[12][512] gather
// ---------------------------------------------------------------------------
__global__ __launch_bounds__(256) void prep_pe(
    const float* __restrict__ emb_b, const float* __restrict__ bq,
    const float* __restrict__ bk, const float* __restrict__ bv,
    u16* __restrict__ A_pe, float* __restrict__ pb_bias) {
  int bid = blockIdx.x, t = threadIdx.x;
  if (bid < 512) {
    int s = bid;
    float div = expf((2.f * t) * (-9.210340371976184f / 512.f));
    float arg = (float)s * div;
    A_pe[s * 512 + 2 * t] = f2b(sinf(arg) + emb_b[2 * t]);
    A_pe[s * 512 + 2 * t + 1] = f2b(cosf(arg) + emb_b[2 * t + 1]);
  } else {
    int i = (bid - 512) * 256 + t;  // 0..6143
    int z = i >> 9, e = i & 511;
    int ty = z >> 2, m = z & 3;
    const float* bp = (ty == 0) ? bq : (ty == 1) ? bk : bv;
    pb_bias[i] = bp[m * 512 + e];
  }
}

// ---------------------------------------------------------------------------
// transpose the 12 QKV weight matrices (fp32 DMxDM, row d, col e) -> bf16 [e][d]
// ---------------------------------------------------------------------------
__global__ __launch_bounds__(256) void transw(
    const float* __restrict__ Wq, const float* __restrict__ Wk,
    const float* __restrict__ Wv, u16* __restrict__ WTqkv) {
  __shared__ float tile[64][65];
  int mid = blockIdx.x;
  const float* W = ((mid < 4) ? Wq : (mid < 8) ? Wk : Wv) + (long)(mid & 3) * 262144;
  u16* WT = WTqkv + (long)mid * 262144;
  int d0 = blockIdx.y * 64, e0 = blockIdx.z * 64;
  int t = threadIdx.x;
  int dr = t >> 2, ec = (t & 3) * 16;
#pragma unroll
  for (int j = 0; j < 16; j += 4) {
    float4 v = *(const float4*)&W[(long)(d0 + dr) * 512 + e0 + ec + j];
    tile[dr][ec + j] = v.x;
    tile[dr][ec + j + 1] = v.y;
    tile[dr][ec + j + 2] = v.z;
    tile[dr][ec + j + 3] = v.w;
  }
  __syncthreads();
  int er = t >> 2, dc = (t & 3) * 16;
  u16 tmp[16] __attribute__((aligned(16)));
#pragma unroll
  for (int j = 0; j < 16; ++j) tmp[j] = f2b(tile[dc + j][er]);
  *(short8*)&WT[(long)(e0 + er) * 512 + d0 + dc] = *(short8*)&tmp[0];
  *(short8*)&WT[(long)(e0 + er) * 512 + d0 + dc + 8] = *(short8*)&tmp[8];
}

// ---------------------------------------------------------------------------
// EW[z][f][e] = sum_d emb_W[f][d] * W_z[d][e]   (z = ty*4+m, ty in {q,k,v})
// ---------------------------------------------------------------------------
__global__ __launch_bounds__(256) void ew_kernel(
    const float* __restrict__ Wq, const float* __restrict__ Wk,
    const float* __restrict__ Wv, const float* __restrict__ embW,
    float* __restrict__ EW) {
  int z = blockIdx.x >> 2;
  int f = blockIdx.x & 3;
  const float* W = ((z < 4) ? Wq : (z < 8) ? Wv - 2097152 + 1048576 : Wv) + (long)(z & 3) * 262144;
  // note: branch kept simple below
  W = ((z < 4) ? Wq : (z < 8) ? Wk : Wv) + (long)(z & 3) * 262144;
  int t = threadIdx.x;
  float a0 = 0.f, a1 = 0.f;
  for (int d = 0; d < 512; ++d) {
    float e = embW[f * 512 + d];
    a0 += e * W[(long)d * 512 + t];
    a1 += e * W[(long)d * 512 + t + 256];
  }
  EW[((long)z * 4 + f) * 512 + t] = a0;
  EW[((long)z * 4 + f) * 512 + t + 256] = a1;
}

// ---------------------------------------------------------------------------
// WEFF_m[d][j] = sum_e Wo_m[d][e] * w1[o][m*512+e][k]   (j = o*3+k, 15 + pad)
// stored transposed: WEFFT[m][j][d] bf16.  Extra block computes bias_t.
// ---------------------------------------------------------------------------
__global__ __launch_bounds__(64) void weff_kernel(
    const float* __restrict__ Wo, const float* __restrict__ bo,
    const float* __restrict__ w1, u16* __restrict__ WEFFT,
    float* __restrict__ bias_t) {
  const int bid = blockIdx.x, l = threadIdx.x;
  if (bid < 2048) {
    int m = bid >> 9, d = bid & 511;
    const float* wrow = Wo + ((long)m * 512 + d) * 512;
    float a[15] = {};
#pragma unroll
    for (int i = 0; i < 8; ++i) {
      int e = l * 8 + i;
      float wv = wrow[e];
#pragma unroll
      for (int o = 0; o < 5; ++o)
#pragma unroll
        for (int k = 0; k < 3; ++k)
          a[o * 3 + k] += wv * w1[((long)o * 2048 + m * 512 + e) * 3 + k];
    }
#pragma unroll
    for (int j = 0; j < 15; ++j) {
      float v = a[j];
      for (int o = 1; o < 64; o <<= 1) v += __shfl_xor(v, o);
      if (l == 0) WEFFT[((long)m * 16 + j) * 512 + d] = f2b(v);
    }
    if (l == 0) WEFFT[((long)m * 16 + 15) * 512 + d] = 0;
  } else {
    float a[15] = {};
    for (int c = l; c < 2048; c += 64) {
      float bv = bo[c];
#pragma unroll
      for (int o = 0; o < 5; ++o)
#pragma unroll
        for (int k = 0; k < 3; ++k)
          a[o * 3 + k] += bv * w1[((long)o * 2048 + c) * 3 + k];
    }
#pragma unroll
    for (int j = 0; j < 15; ++j) {
      float v = a[j];
      for (int o = 1; o < 64; o <<= 1) v += __shfl_xor(v, o);
      if (l == 0) bias_t[j] = v;
    }
    if (l == 0) bias_t[15] = 0.f;
  }
}

// ---------------------------------------------------------------------------
// generic bf16 GEMM  C[r][c] = sum_k A[r][k] * BT[c][k] + bias[c]
// ---------------------------------------------------------------------------
template <bool OBF>
__global__ __launch_bounds__(256) void gemm_bt(
    const u16* __restrict__ A, long sAz, int lda, const u16* __restrict__ BT,
    const float* __restrict__ bias, void* __restrict__ out, long sOz, int ldo) {
  __shared__ u16 As[128 * 32];
  __shared__ u16 Bs[128 * 32];
  const int z = blockIdx.z;
  const int tid = threadIdx.x, w = tid >> 6, l = tid & 63;
  const long row0 = (long)blockIdx.y * 128;
  const u16* Ab = A + (long)z * sAz + row0 * lda;
  const u16* Bb = BT + (long)z * 262144 + (long)blockIdx.x * 128 * 512;
  const u16* ga = Ab + (long)(w * 32 + (l >> 2)) * lda + (l & 3) * 8;
  const u16* gb = Bb + (long)(w * 32 + (l >> 2)) * 512 + (l & 3) * 8;
  u16* lA = As + w * 32 * 32;
  u16* lB = Bs + w * 32 * 32;
  f32x4 acc[4][4] = {};
  const int wr = (w >> 1) * 64, wc = (w & 1) * 64;
  for (int kt = 0; kt < 16; ++kt) {
    gload16(ga + kt * 32, lA);
    gload16(ga + kt * 32 + 16 * lda, lA + 16 * 32);
    gload16(gb + kt * 32, lB);
    gload16(gb + kt * 32 + 16 * 512, lB + 16 * 32);
    __syncthreads();
    short8 af[4], bf[4];
#pragma unroll
    for (int i = 0; i < 4; ++i)
      af[i] = *(const short8*)&As[(wr + i * 16 + (l & 15)) * 32 + (l >> 4) * 8];
#pragma unroll
    for (int i = 0; i < 4; ++i)
      bf[i] = *(const short8*)&Bs[(wc + i * 16 + (l & 15)) * 32 + (l >> 4) * 8];
#pragma unroll
    for (int i = 0; i < 4; ++i)
#pragma unroll
      for (int j = 0; j < 4; ++j) acc[i][j] = mfma16(af[i], bf[j], acc[i][j]);
    __syncthreads();
  }
  const int colB = blockIdx.x * 128 + wc;
#pragma unroll
  for (int i = 0; i < 4; ++i)
#pragma unroll
    for (int j = 0; j < 4; ++j) {
      int col = colB + j * 16 + (l & 15);
      float bb = bias[(long)z * 512 + col];
#pragma unroll
      for (int q = 0; q < 4; ++q) {
        long r = row0 + wr + i * 16 + (l >> 4) * 4 + q;
        float v = acc[i][j][q] + bb;
        if (OBF)
          ((u16*)out)[(long)z * sOz + r * ldo + col] = f2b(v);
        else
          ((float*)out)[(long)z * sOz + r * ldo + col] = v;
      }
    }
}

// ---------------------------------------------------------------------------
// QKV generation for module m: rank-4 update + PB table (bf16), fused L2 norm
// ---------------------------------------------------------------------------
__global__ __launch_bounds__(256) void qkv_gen(
    const float* __restrict__ x, const float* __restrict__ EW,
    const u16* __restrict__ PB, u16* __restrict__ Qm, u16* __restrict__ Km,
    u16* __restrict__ Vm, int m) {
  const int rid = blockIdx.x;  // b*512+s
  const int s = rid & 511;
  const int t = threadIdx.x;
  const float* xr = x + (long)rid * 7;
  const float xd = xr[3 + m], x0 = xr[0], x1 = xr[1], x2 = xr[2];
  float2 res[3];
#pragma unroll
  for (int ty = 0; ty < 3; ++ty) {
    int z = ty * 4 + m;
    const float* ew = EW + (long)z * 4 * 512;
    float2 e0 = *(const float2*)&ew[0 * 512 + 2 * t];
    float2 e1 = *(const float2*)&ew[1 * 512 + 2 * t];
    float2 e2 = *(const float2*)&ew[2 * 512 + 2 * t];
    float2 e3 = *(const float2*)&ew[3 * 512 + 2 * t];
    u32 pb2 = *(const u32*)&PB[((long)z * 512 + s) * 512 + 2 * t];
    res[ty].x = xd * e0.x + x0 * e1.x + x1 * e2.x + x2 * e3.x + b2f((u16)pb2);
    res[ty].y =
        xd * e0.y + x0 * e1.y + x1 * e2.y + x2 * e3.y + b2f((u16)(pb2 >> 16));
  }
  const long obase = (long)rid * 512 + 2 * t;
  *(u32*)&Vm[obase] = pk2(res[2].x, res[2].y);
#pragma unroll
  for (int ty = 0; ty < 2; ++ty) {
    float ss = res[ty].x * res[ty].x + res[ty].y * res[ty].y;
    for (int o = 1; o < 32; o <<= 1) ss += __shfl_xor(ss, o);
    float sc = 1.f / fmaxf(sqrtf(ss), 1e-12f);
    u16* P = ty ? Km : Qm;
    *(u32*)&P[obase] = pk2(res[ty].x * sc, res[ty].y * sc);
  }
}

// ---------------------------------------------------------------------------
// V transpose per module: VT[(b*8+h)*64 + dk][s] = V[(b*512+s)][h*64+dk]
// ---------------------------------------------------------------------------
__global__ __launch_bounds__(256) void vtrans(const u16* __restrict__ V,
                                              u16* __restrict__ VT) {
  __shared__ u16 tile[64][72];
  int bh = blockIdx.x;
  int b = bh >> 3, h = bh & 7;
  int st = blockIdx.y;
  int t = threadIdx.x;
  int sr = t >> 2, kc = (t & 3) * 16;
  long gsrc = ((long)b * 512 + st * 64 + sr) * 512 + h * 64 + kc;
  *(short8*)&tile[sr][kc] = *(const short8*)&V[gsrc];
  *(short8*)&tile[sr][kc + 8] = *(const short8*)&V[gsrc + 8];
  __syncthreads();
  int kr = t >> 2, sc = (t & 3) * 16;
  u16 tmp[16] __attribute__((aligned(16)));
#pragma unroll
  for (int j = 0; j < 16; ++j) tmp[j] = tile[sc + j][kr];
  long gdst = ((long)bh * 64 + kr) * 512 + st * 64 + sc;
  *(short8*)&VT[gdst] = *(short8*)&tmp[0];
  *(short8*)&VT[gdst + 8] = *(short8*)&tmp[8];
}

// ---------------------------------------------------------------------------
// flash attention, max-free: scores are cosines in [-1,1] (Q,K L2-normed),
// so P = exp(S) directly; row-sum l via ones-MFMA; divide at the end.
// block = (b*8+h, qb of 128 rows), 4 waves, wave handles 32 q-rows.
// ---------------------------------------------------------------------------
__global__ __launch_bounds__(256) void attn_kernel(
    const u16* __restrict__ Q, const u16* __restrict__ K,
    const u16* __restrict__ VT, u16* __restrict__ ctx) {
  __shared__ u16 Ks[64][72];
  __shared__ u16 Vts[64][72];
  __shared__ u16 Ps[4][32][72];
  const int bh = blockIdx.x;  // b*8+h
  const int qb = blockIdx.y;
  const int b = bh >> 3, h = bh & 7;
  const int tid = threadIdx.x, w = tid >> 6, l = tid & 63;
  const long rowbase = (long)b * 512;
  const int hoff = h * 64;

  // Q fragments straight from global (L3-resident; one-time read)
  short8 qf[2][2];
#pragma unroll
  for (int rt = 0; rt < 2; ++rt)
#pragma unroll
    for (int kk = 0; kk < 2; ++kk)
      qf[rt][kk] = *(const short8*)&Q[(rowbase + qb * 128 + w * 32 + rt * 16 +
                                       (l & 15)) *
                                          512 +
                                      hoff + kk * 32 + (l >> 4) * 8];

  short8 ones;
#pragma unroll
  for (int i = 0; i < 8; ++i) ones[i] = (short)0x3F80;  // bf16 1.0

  f32x4 o_acc[2][4] = {};
  f32x4 l_acc[2] = {};

  for (int kt = 0; kt < 8; ++kt) {
    __syncthreads();
#pragma unroll
    for (int t = 0; t < 2; ++t) {
      int c = tid + t * 256;
      int tr = c >> 3, cc = c & 7;
      *(short8*)&Ks[tr][cc * 8] =
          *(const short8*)&K[(rowbase + kt * 64 + tr) * 512 + hoff + cc * 8];
      *(short8*)&Vts[tr][cc * 8] =
          *(const short8*)&VT[((long)bh * 64 + tr) * 512 + kt * 64 + cc * 8];
    }
    __syncthreads();
    f32x4 s_acc[2][4] = {};
#pragma unroll
    for (int kk = 0; kk < 2; ++kk) {
      short8 bfr[4];
#pragma unroll
      for (int nt = 0; nt < 4; ++nt)
        bfr[nt] = *(const short8*)&Ks[nt * 16 + (l & 15)][kk * 32 + (l >> 4) * 8];
#pragma unroll
      for (int rt = 0; rt < 2; ++rt)
#pragma unroll
        for (int nt = 0; nt < 4; ++nt)
          s_acc[rt][nt] = mfma16(qf[rt][kk], bfr[nt], s_acc[rt][nt]);
    }
    // P = exp(S) (bounded: |S| <= ~1), store per-wave P tile (no barrier)
#pragma unroll
    for (int rt = 0; rt < 2; ++rt)
#pragma unroll
      for (int nt = 0; nt < 4; ++nt)
#pragma unroll
        for (int q = 0; q < 4; ++q)
          Ps[w][rt * 16 + (l >> 4) * 4 + q][nt * 16 + (l & 15)] =
              f2b(__expf(s_acc[rt][nt][q]));
#pragma unroll
    for (int kk = 0; kk < 2; ++kk) {
      short8 pa[2], vb[4];
#pragma unroll
      for (int rt = 0; rt < 2; ++rt)
        pa[rt] =
            *(const short8*)&Ps[w][rt * 16 + (l & 15)][kk * 32 + (l >> 4) * 8];
#pragma unroll
      for (int dt = 0; dt < 4; ++dt)
        vb[dt] =
            *(const short8*)&Vts[dt * 16 + (l & 15)][kk * 32 + (l >> 4) * 8];
#pragma unroll
      for (int rt = 0; rt < 2; ++rt) {
        l_acc[rt] = mfma16(pa[rt], ones, l_acc[rt]);
#pragma unroll
        for (int dt = 0; dt < 4; ++dt)
          o_acc[rt][dt] = mfma16(pa[rt], vb[dt], o_acc[rt][dt]);
      }
    }
  }
#pragma unroll
  for (int rt = 0; rt < 2; ++rt)
#pragma unroll
    for (int q = 0; q < 4; ++q) {
      float inv = 1.f / l_acc[rt][q];
      int r = qb * 128 + w * 32 + rt * 16 + (l >> 4) * 4 + q;
#pragma unroll
      for (int dt = 0; dt < 4; ++dt)
        ctx[(rowbase + r) * 512 + hoff + dt * 16 + (l & 15)] =
            f2b(o_acc[rt][dt][q] * inv);
    }
}

// ---------------------------------------------------------------------------
// t[r][j] = sum_m ctx_m[r][:] . WEFFT[m][j][:]   (r = b*512+s, j = o*3+k)
// ---------------------------------------------------------------------------
__global__ __launch_bounds__(64) void t_gemm(const u16* __restrict__ ctx4,
                                             const u16* __restrict__ WEFFT,
                                             float* __restrict__ t) {
  const int l = threadIdx.x;
  const long r0 = (long)blockIdx.x * 16;
  f32x4 acc = {};
#pragma unroll
  for (int m = 0; m < 4; ++m) {
    const u16* A =
        ctx4 + (long)m * 8388608 + (r0 + (l & 15)) * 512 + (l >> 4) * 8;
    const u16* Bb = WEFFT + m * 8192 + (l & 15) * 512 + (l >> 4) * 8;
#pragma unroll
    for (int kt = 0; kt < 16; ++kt) {
      short8 af = *(const short8*)(A + kt * 32);
      short8 bf = *(const short8*)(Bb + kt * 32);
      acc = mfma16(af, bf, acc);
    }
  }
#pragma unroll
  for (int q = 0; q < 4; ++q)
    t[(r0 + (l >> 4) * 4 + q) * 16 + (l & 15)] = acc[q];
}

// ---------------------------------------------------------------------------
// c1[b][o][s] = elu(b1[o] + sum_k in-range (t[b,s+k-1,o*3+k] + bias_t[o*3+k]))
// ---------------------------------------------------------------------------
__global__ __launch_bounds__(256) void c1_kernel(
    const float* __restrict__ t, const float* __restrict__ bias_t,
    const float* __restrict__ b1, float* __restrict__ c1) {
  int idx = blockIdx.x * 256 + threadIdx.x;  // (b*5+o)*512+s
  int s = idx & 511;
  int rest = idx >> 9;
  int o = rest % 5, b = rest / 5;
  float a = b1[o];
  long base = (long)b * 512;
#pragma unroll
  for (int k = 0; k < 3; ++k) {
    int ss = s + k - 1;
    if (ss >= 0 && ss < 512)
      a += t[(base + ss) * 16 + o * 3 + k] + bias_t[o * 3 + k];
  }
  c1[idx] = eluf(a);
}

// ---------------------------------------------------------------------------
// conv2 + elu + pairwise max-pool -> flat (32 x 512)
// ---------------------------------------------------------------------------
__global__ __launch_bounds__(256) void conv2pool(const float* __restrict__ c1,
                                                 const float* __restrict__ w2,
                                                 const float* __restrict__ b2,
                                                 float* __restrict__ flat) {
  int idx = blockIdx.x * 256 + threadIdx.x;  // 0..16383
  int b = idx >> 9, r = idx & 511, o = r >> 8, sp = r & 255;
  float mx = -1e30f;
#pragma unroll
  for (int sd = 0; sd < 2; ++sd) {
    int s = sp * 2 + sd;
    float a = b2[o];
#pragma unroll
    for (int ic = 0; ic < 5; ++ic)
#pragma unroll
      for (int k = 0; k < 3; ++k) {
        int ss = s + k - 1;
        if (ss >= 0 && ss < 512)
          a += c1[((long)b * 5 + ic) * 512 + ss] * w2[(o * 5 + ic) * 3 + k];
      }
    mx = fmaxf(mx, eluf(a));
  }
  flat[idx] = mx;
}

// ---------------------------------------------------------------------------
// FC head + LayerNorm, one block per batch element
// ---------------------------------------------------------------------------
__global__ __launch_bounds__(256) void head_kernel(
    const float* __restrict__ flat, const float* __restrict__ w1,
    const float* __restrict__ b1, const float* __restrict__ w2,
    const float* __restrict__ b2, const float* __restrict__ w3,
    const float* __restrict__ b3, const float* __restrict__ g,
    const float* __restrict__ be, float* __restrict__ out) {
  __shared__ float xb[512], z1[256], z2[128], z3[96];
  int b = blockIdx.x, t = threadIdx.x;
  xb[t] = flat[b * 512 + t];
  xb[t + 256] = flat[b * 512 + t + 256];
  __syncthreads();
  {
    float a = b1[t];
    for (int i = 0; i < 512; ++i) a += xb[i] * w1[i * 256 + t];
    z1[t] = eluf(a);
  }
  __syncthreads();
  if (t < 128) {
    float a = b2[t];
    for (int i = 0; i < 256; ++i) a += z1[i] * w2[i * 128 + t];
    z2[t] = eluf(a);
  }
  __syncthreads();
  if (t < 96) {
    float a = b3[t];
    for (int i = 0; i < 128; ++i) a += z2[i] * w3[i * 96 + t];
    z3[t] = a;
  }
  __syncthreads();
  if (t < 96) {
    float mu = 0.f;
    for (int j = 0; j < 96; ++j) mu += z3[j];
    mu *= (1.f / 96.f);
    float sq = 0.f;
    for (int j = 0; j < 96; ++j) {
      float d = z3[j] - mu;
      sq += d * d;
    }
    float var = sq * (1.f / 96.f);
    out[b * 96 + t] = (z3[t] - mu) / sqrtf(var + 1e-5f) * g[t] + be[t];
  }
}

// ---------------------------------------------------------------------------
extern "C" void kernel_launch(void* const* d_in, const int* in_sizes, int n_in,
                              void* d_out, int out_size, void* d_ws,
                              size_t ws_size, hipStream_t stream) {
  (void)in_sizes; (void)n_in; (void)out_size;
  const float* x    = (const float*)d_in[0];
  const float* embW = (const float*)d_in[1];
  const float* embB = (const float*)d_in[2];
  const float* Wq   = (const float*)d_in[3];
  const float* bq   = (const float*)d_in[4];
  const float* Wk   = (const float*)d_in[5];
  const float* bk   = (const float*)d_in[6];
  const float* Wv   = (const float*)d_in[7];
  const float* bv   = (const float*)d_in[8];
  const float* Wo   = (const float*)d_in[9];
  const float* bo   = (const float*)d_in[10];
  const float* c1w  = (const float*)d_in[11];
  const float* c1b  = (const float*)d_in[12];
  const float* c2w  = (const float*)d_in[13];
  const float* c2b  = (const float*)d_in[14];
  const float* f1w  = (const float*)d_in[15];
  const float* f1b  = (const float*)d_in[16];
  const float* f2w  = (const float*)d_in[17];
  const float* f2b_ = (const float*)d_in[18];
  const float* f3w  = (const float*)d_in[19];
  const float* f3b  = (const float*)d_in[20];
  const float* lng  = (const float*)d_in[21];
  const float* lnb  = (const float*)d_in[22];
  float* out = (float*)d_out;

  char* p = (char*)d_ws;
  const size_t NEED = 148955200;
  if (ws_size < NEED) return;
  u16*   A_pe    = (u16*)(p + 0);           //   512x512 bf16
  u16*   WTqkv   = (u16*)(p + 524288);      //  12x512x512 bf16
  float* pb_bias = (float*)(p + 6815744);   //  12x512 f32
  float* EW      = (float*)(p + 6840320);   //  12x4x512 f32
  u16*   PB      = (u16*)(p + 6938624);     //  12x512x512 bf16
  u16*   Qm      = (u16*)(p + 13230080);    //  16384x512 bf16
  u16*   Km      = (u16*)(p + 30007296);
  u16*   Vm      = (u16*)(p + 46784512);
  u16*   VTm     = (u16*)(p + 63561728);
  u16*   ctx4    = (u16*)(p + 80338944);    //  4x16384x512 bf16
  u16*   WEFFT   = (u16*)(p + 147447808);   //  4x16x512 bf16
  float* bias_t  = (float*)(p + 147513344); //  16 f32
  float* t_buf   = (float*)(p + 147513408); //  16384x16 f32
  float* c1buf   = (float*)(p + 148561984); //  32x5x512 f32
  float* flat    = (float*)(p + 148889664); //  32x512 f32

  prep_pe<<<536, 256, 0, stream>>>(embB, bq, bk, bv, A_pe, pb_bias);
  transw<<<dim3(12, 8, 8), 256, 0, stream>>>(Wq, Wk, Wv, WTqkv);
  ew_kernel<<<48, 256, 0, stream>>>(Wq, Wk, Wv, embW, EW);
  weff_kernel<<<2049, 64, 0, stream>>>(Wo, bo, c1w, WEFFT, bias_t);
  // PB[z] = (PE+emb_b) @ W_z + bias_z   (bf16 out)
  gemm_bt<true><<<dim3(4, 4, 12), 256, 0, stream>>>(
      A_pe, 0, 512, WTqkv, pb_bias, (void*)PB, 262144, 512);

  for (int m = 0; m < 4; ++m) {
    qkv_gen<<<16384, 256, 0, stream>>>(x, EW, PB, Qm, Km, Vm, m);
    vtrans<<<dim3(256, 8), 256, 0, stream>>>(Vm, VTm);
    attn_kernel<<<dim3(256, 4), 256, 0, stream>>>(
        Qm, Km, VTm, ctx4 + (long)m * 8388608);
  }

  t_gemm<<<1024, 64, 0, stream>>>(ctx4, WEFFT, t_buf);
  c1_kernel<<<320, 256, 0, stream>>>(t_buf, bias_t, c1b, c1buf);
  conv2pool<<<64, 256, 0, stream>>>(c1buf, c2w, c2b, flat);
  head_kernel<<<32, 256, 0, stream>>>(flat, f1w, f1b, f2w, f2b_, f3w, f3b,
                                      lng, lnb, out);
}

// Round 4
// 405.911 us; speedup vs baseline: 1.6290x; 1.1115x over previous
//
#include <hip/hip_runtime.h>
#include <math.h>

typedef unsigned short u16;
typedef unsigned int u32;
typedef __attribute__((ext_vector_type(8))) short short8;
typedef __attribute__((ext_vector_type(4))) float f32x4;

__device__ inline u16 f2b(float f) {
  u32 u = __builtin_bit_cast(u32, f);
  u32 r = u + 0x7fffu + ((u >> 16) & 1u);
  return (u16)(r >> 16);
}
__device__ inline float b2f(u16 b) {
  return __builtin_bit_cast(float, (u32)b << 16);
}
__device__ inline u32 pk2(float a, float b) {
  return (u32)f2b(a) | ((u32)f2b(b) << 16);
}
__device__ inline float eluf(float x) { return x > 0.f ? x : expf(x) - 1.f; }

__device__ inline f32x4 mfma16(short8 a, short8 b, f32x4 c) {
  return __builtin_amdgcn_mfma_f32_16x16x32_bf16(a, b, c, 0, 0, 0);
}
__device__ inline void gload16(const u16* g, u16* l) {
  __builtin_amdgcn_global_load_lds((__attribute__((address_space(1))) void*)(g),
                                   (__attribute__((address_space(3))) void*)(l),
                                   16, 0, 0);
}

// ---------------------------------------------------------------------------
// prep: A_pe[s][d] = PE[s][d] + emb_b[d]  (bf16)   and pb_bias[12][512] gather
// ---------------------------------------------------------------------------
__global__ __launch_bounds__(256) void prep_pe(
    const float* __restrict__ emb_b, const float* __restrict__ bq,
    const float* __restrict__ bk, const float* __restrict__ bv,
    u16* __restrict__ A_pe, float* __restrict__ pb_bias) {
  int bid = blockIdx.x, t = threadIdx.x;
  if (bid < 512) {
    int s = bid;
    float div = expf((2.f * t) * (-9.210340371976184f / 512.f));
    float arg = (float)s * div;
    A_pe[s * 512 + 2 * t] = f2b(sinf(arg) + emb_b[2 * t]);
    A_pe[s * 512 + 2 * t + 1] = f2b(cosf(arg) + emb_b[2 * t + 1]);
  } else {
    int i = (bid - 512) * 256 + t;  // 0..6143
    int z = i >> 9, e = i & 511;
    int ty = z >> 2, m = z & 3;
    const float* bp = (ty == 0) ? bq : (ty == 1) ? bk : bv;
    pb_bias[i] = bp[m * 512 + e];
  }
}

// ---------------------------------------------------------------------------
// transpose the 12 QKV weight matrices (fp32 DMxDM, row d, col e) -> bf16 [e][d]
// ---------------------------------------------------------------------------
__global__ __launch_bounds__(256) void transw(
    const float* __restrict__ Wq, const float* __restrict__ Wk,
    const float* __restrict__ Wv, u16* __restrict__ WTqkv) {
  __shared__ float tile[64][65];
  int mid = blockIdx.x;
  const float* W = ((mid < 4) ? Wq : (mid < 8) ? Wk : Wv) + (long)(mid & 3) * 262144;
  u16* WT = WTqkv + (long)mid * 262144;
  int d0 = blockIdx.y * 64, e0 = blockIdx.z * 64;
  int t = threadIdx.x;
  int dr = t >> 2, ec = (t & 3) * 16;
#pragma unroll
  for (int j = 0; j < 16; j += 4) {
    float4 v = *(const float4*)&W[(long)(d0 + dr) * 512 + e0 + ec + j];
    tile[dr][ec + j] = v.x;
    tile[dr][ec + j + 1] = v.y;
    tile[dr][ec + j + 2] = v.z;
    tile[dr][ec + j + 3] = v.w;
  }
  __syncthreads();
  int er = t >> 2, dc = (t & 3) * 16;
  u16 tmp[16] __attribute__((aligned(16)));
#pragma unroll
  for (int j = 0; j < 16; ++j) tmp[j] = f2b(tile[dc + j][er]);
  *(short8*)&WT[(long)(e0 + er) * 512 + d0 + dc] = *(short8*)&tmp[0];
  *(short8*)&WT[(long)(e0 + er) * 512 + d0 + dc + 8] = *(short8*)&tmp[8];
}

// ---------------------------------------------------------------------------
// EW[z][f][e] = sum_d emb_W[f][d] * W_z[d][e]   (z = ty*4+m, ty in {q,k,v})
// ---------------------------------------------------------------------------
__global__ __launch_bounds__(256) void ew_kernel(
    const float* __restrict__ Wq, const float* __restrict__ Wk,
    const float* __restrict__ Wv, const float* __restrict__ embW,
    float* __restrict__ EW) {
  int z = blockIdx.x >> 2;
  int f = blockIdx.x & 3;
  const float* W = ((z < 4) ? Wq : (z < 8) ? Wk : Wv) + (long)(z & 3) * 262144;
  int t = threadIdx.x;
  float a0 = 0.f, a1 = 0.f;
  for (int d = 0; d < 512; ++d) {
    float e = embW[f * 512 + d];
    a0 += e * W[(long)d * 512 + t];
    a1 += e * W[(long)d * 512 + t + 256];
  }
  EW[((long)z * 4 + f) * 512 + t] = a0;
  EW[((long)z * 4 + f) * 512 + t + 256] = a1;
}

// ---------------------------------------------------------------------------
// WEFF_m[d][j] = sum_e Wo_m[d][e] * w1[o][m*512+e][k]   (j = o*3+k, 15 + pad)
// stored transposed: WEFFT[m][j][d] bf16.  Extra block computes bias_t.
// ---------------------------------------------------------------------------
__global__ __launch_bounds__(64) void weff_kernel(
    const float* __restrict__ Wo, const float* __restrict__ bo,
    const float* __restrict__ w1, u16* __restrict__ WEFFT,
    float* __restrict__ bias_t) {
  const int bid = blockIdx.x, l = threadIdx.x;
  if (bid < 2048) {
    int m = bid >> 9, d = bid & 511;
    const float* wrow = Wo + ((long)m * 512 + d) * 512;
    float a[15] = {};
#pragma unroll
    for (int i = 0; i < 8; ++i) {
      int e = l * 8 + i;
      float wv = wrow[e];
#pragma unroll
      for (int o = 0; o < 5; ++o)
#pragma unroll
        for (int k = 0; k < 3; ++k)
          a[o * 3 + k] += wv * w1[((long)o * 2048 + m * 512 + e) * 3 + k];
    }
#pragma unroll
    for (int j = 0; j < 15; ++j) {
      float v = a[j];
      for (int o = 1; o < 64; o <<= 1) v += __shfl_xor(v, o);
      if (l == 0) WEFFT[((long)m * 16 + j) * 512 + d] = f2b(v);
    }
    if (l == 0) WEFFT[((long)m * 16 + 15) * 512 + d] = 0;
  } else {
    float a[15] = {};
    for (int c = l; c < 2048; c += 64) {
      float bv = bo[c];
#pragma unroll
      for (int o = 0; o < 5; ++o)
#pragma unroll
        for (int k = 0; k < 3; ++k)
          a[o * 3 + k] += bv * w1[((long)o * 2048 + c) * 3 + k];
    }
#pragma unroll
    for (int j = 0; j < 15; ++j) {
      float v = a[j];
      for (int o = 1; o < 64; o <<= 1) v += __shfl_xor(v, o);
      if (l == 0) bias_t[j] = v;
    }
    if (l == 0) bias_t[15] = 0.f;
  }
}

// ---------------------------------------------------------------------------
// generic bf16 GEMM  C[r][c] = sum_k A[r][k] * BT[c][k] + bias[c]
// ---------------------------------------------------------------------------
template <bool OBF>
__global__ __launch_bounds__(256) void gemm_bt(
    const u16* __restrict__ A, long sAz, int lda, const u16* __restrict__ BT,
    const float* __restrict__ bias, void* __restrict__ out, long sOz, int ldo) {
  __shared__ u16 As[128 * 32];
  __shared__ u16 Bs[128 * 32];
  const int z = blockIdx.z;
  const int tid = threadIdx.x, w = tid >> 6, l = tid & 63;
  const long row0 = (long)blockIdx.y * 128;
  const u16* Ab = A + (long)z * sAz + row0 * lda;
  const u16* Bb = BT + (long)z * 262144 + (long)blockIdx.x * 128 * 512;
  const u16* ga = Ab + (long)(w * 32 + (l >> 2)) * lda + (l & 3) * 8;
  const u16* gb = Bb + (long)(w * 32 + (l >> 2)) * 512 + (l & 3) * 8;
  u16* lA = As + w * 32 * 32;
  u16* lB = Bs + w * 32 * 32;
  f32x4 acc[4][4] = {};
  const int wr = (w >> 1) * 64, wc = (w & 1) * 64;
  for (int kt = 0; kt < 16; ++kt) {
    gload16(ga + kt * 32, lA);
    gload16(ga + kt * 32 + 16 * lda, lA + 16 * 32);
    gload16(gb + kt * 32, lB);
    gload16(gb + kt * 32 + 16 * 512, lB + 16 * 32);
    __syncthreads();
    short8 af[4], bf[4];
#pragma unroll
    for (int i = 0; i < 4; ++i)
      af[i] = *(const short8*)&As[(wr + i * 16 + (l & 15)) * 32 + (l >> 4) * 8];
#pragma unroll
    for (int i = 0; i < 4; ++i)
      bf[i] = *(const short8*)&Bs[(wc + i * 16 + (l & 15)) * 32 + (l >> 4) * 8];
#pragma unroll
    for (int i = 0; i < 4; ++i)
#pragma unroll
      for (int j = 0; j < 4; ++j) acc[i][j] = mfma16(af[i], bf[j], acc[i][j]);
    __syncthreads();
  }
  const int colB = blockIdx.x * 128 + wc;
#pragma unroll
  for (int i = 0; i < 4; ++i)
#pragma unroll
    for (int j = 0; j < 4; ++j) {
      int col = colB + j * 16 + (l & 15);
      float bb = bias[(long)z * 512 + col];
#pragma unroll
      for (int q = 0; q < 4; ++q) {
        long r = row0 + wr + i * 16 + (l >> 4) * 4 + q;
        float v = acc[i][j][q] + bb;
        if (OBF)
          ((u16*)out)[(long)z * sOz + r * ldo + col] = f2b(v);
        else
          ((float*)out)[(long)z * sOz + r * ldo + col] = v;
      }
    }
}

// ---------------------------------------------------------------------------
// QKV generation for module m: rank-4 update + PB table (bf16), fused L2 norm
// ---------------------------------------------------------------------------
__global__ __launch_bounds__(256) void qkv_gen(
    const float* __restrict__ x, const float* __restrict__ EW,
    const u16* __restrict__ PB, u16* __restrict__ Qm, u16* __restrict__ Km,
    u16* __restrict__ Vm, int m) {
  const int rid = blockIdx.x;  // b*512+s
  const int s = rid & 511;
  const int t = threadIdx.x;
  const float* xr = x + (long)rid * 7;
  const float xd = xr[3 + m], x0 = xr[0], x1 = xr[1], x2 = xr[2];
  float2 res[3];
#pragma unroll
  for (int ty = 0; ty < 3; ++ty) {
    int z = ty * 4 + m;
    const float* ew = EW + (long)z * 4 * 512;
    float2 e0 = *(const float2*)&ew[0 * 512 + 2 * t];
    float2 e1 = *(const float2*)&ew[1 * 512 + 2 * t];
    float2 e2 = *(const float2*)&ew[2 * 512 + 2 * t];
    float2 e3 = *(const float2*)&ew[3 * 512 + 2 * t];
    u32 pb2 = *(const u32*)&PB[((long)z * 512 + s) * 512 + 2 * t];
    res[ty].x = xd * e0.x + x0 * e1.x + x1 * e2.x + x2 * e3.x + b2f((u16)pb2);
    res[ty].y =
        xd * e0.y + x0 * e1.y + x1 * e2.y + x2 * e3.y + b2f((u16)(pb2 >> 16));
  }
  const long obase = (long)rid * 512 + 2 * t;
  *(u32*)&Vm[obase] = pk2(res[2].x, res[2].y);
#pragma unroll
  for (int ty = 0; ty < 2; ++ty) {
    float ss = res[ty].x * res[ty].x + res[ty].y * res[ty].y;
    for (int o = 1; o < 32; o <<= 1) ss += __shfl_xor(ss, o);
    float sc = 1.f / fmaxf(sqrtf(ss), 1e-12f);
    u16* P = ty ? Km : Qm;
    *(u32*)&P[obase] = pk2(res[ty].x * sc, res[ty].y * sc);
  }
}

// ---------------------------------------------------------------------------
// V transpose per module: VT[(b*8+h)*64 + dk][s] = V[(b*512+s)][h*64+dk]
// ---------------------------------------------------------------------------
__global__ __launch_bounds__(256) void vtrans(const u16* __restrict__ V,
                                              u16* __restrict__ VT) {
  __shared__ u16 tile[64][72];
  int bh = blockIdx.x;
  int b = bh >> 3, h = bh & 7;
  int st = blockIdx.y;
  int t = threadIdx.x;
  int sr = t >> 2, kc = (t & 3) * 16;
  long gsrc = ((long)b * 512 + st * 64 + sr) * 512 + h * 64 + kc;
  *(short8*)&tile[sr][kc] = *(const short8*)&V[gsrc];
  *(short8*)&tile[sr][kc + 8] = *(const short8*)&V[gsrc + 8];
  __syncthreads();
  int kr = t >> 2, sc = (t & 3) * 16;
  u16 tmp[16] __attribute__((aligned(16)));
#pragma unroll
  for (int j = 0; j < 16; ++j) tmp[j] = tile[sc + j][kr];
  long gdst = ((long)bh * 64 + kr) * 512 + st * 64 + sc;
  *(short8*)&VT[gdst] = *(short8*)&tmp[0];
  *(short8*)&VT[gdst + 8] = *(short8*)&tmp[8];
}

// ---------------------------------------------------------------------------
// flash attention, max-free (Q,K L2-normed => |S|<=~1 => P=exp(S) directly).
// Double-buffered K/V via global_load_lds into unpadded [64][64] tiles with
// both-sides XOR chunk swizzle; ONE barrier per KV tile; prefetch overlaps
// compute. Row-sum l via ones-MFMA.
// ---------------------------------------------------------------------------
__global__ __launch_bounds__(256) void attn_kernel(
    const u16* __restrict__ Q, const u16* __restrict__ K,
    const u16* __restrict__ VT, u16* __restrict__ ctx) {
  __shared__ u16 Kb[2][64][64];
  __shared__ u16 Vb[2][64][64];
  __shared__ u16 Ps[4][32][72];
  const int bh = blockIdx.x;  // b*8+h
  const int qb = blockIdx.y;
  const int b = bh >> 3, h = bh & 7;
  const int tid = threadIdx.x, w = tid >> 6, l = tid & 63;
  const long rowbase = (long)b * 512;
  const int hoff = h * 64;

  const int rw = l >> 3;         // row within 8-row stripe this lane fills
  const int gch = (l & 7) ^ rw;  // pre-swizzled global 16B-chunk index

  // Q fragments straight from global (L3-resident; one-time read)
  short8 qf[2][2];
#pragma unroll
  for (int rt = 0; rt < 2; ++rt)
#pragma unroll
    for (int kk = 0; kk < 2; ++kk)
      qf[rt][kk] = *(const short8*)&Q[(rowbase + qb * 128 + w * 32 + rt * 16 +
                                       (l & 15)) *
                                          512 +
                                      hoff + kk * 32 + (l >> 4) * 8];

  short8 ones;
#pragma unroll
  for (int i = 0; i < 8; ++i) ones[i] = (short)0x3F80;  // bf16 1.0

  f32x4 o_acc[2][4] = {};
  f32x4 l_acc[2] = {};

  const u16* Kgbase = K + rowbase * 512 + hoff + gch * 8;
  const u16* Vgbase = VT + (long)bh * 64 * 512 + gch * 8;

#define STAGE(bf, kt)                                                         \
  {                                                                           \
    _Pragma("unroll") for (int i = 0; i < 2; ++i) {                           \
      int rr = w * 16 + i * 8;                                                \
      gload16(Kgbase + (long)((kt)*64 + rr + rw) * 512, &Kb[bf][rr][0]);      \
      gload16(Vgbase + (long)(rr + rw) * 512 + (kt)*64, &Vb[bf][rr][0]);      \
    }                                                                         \
  }

  STAGE(0, 0);
  __syncthreads();

  for (int kt = 0; kt < 8; ++kt) {
    const int cur = kt & 1;
    if (kt < 7) STAGE(cur ^ 1, kt + 1);  // async prefetch, in flight
    // QK^T
    f32x4 s_acc[2][4] = {};
#pragma unroll
    for (int kk = 0; kk < 2; ++kk) {
      short8 bfr[4];
#pragma unroll
      for (int nt = 0; nt < 4; ++nt) {
        int R = nt * 16 + (l & 15);
        int ch = ((kk << 2) + (l >> 4)) ^ (l & 7);
        bfr[nt] =
            *(const short8*)((const char*)&Kb[cur][0][0] + R * 128 + ch * 16);
      }
#pragma unroll
      for (int rt = 0; rt < 2; ++rt)
#pragma unroll
        for (int nt = 0; nt < 4; ++nt)
          s_acc[rt][nt] = mfma16(qf[rt][kk], bfr[nt], s_acc[rt][nt]);
    }
    // P = exp(S), bounded by e; per-wave P tile (no cross-wave barrier)
#pragma unroll
    for (int rt = 0; rt < 2; ++rt)
#pragma unroll
      for (int nt = 0; nt < 4; ++nt)
#pragma unroll
        for (int q = 0; q < 4; ++q)
          Ps[w][rt * 16 + (l >> 4) * 4 + q][nt * 16 + (l & 15)] =
              f2b(__expf(s_acc[rt][nt][q]));
    // PV + row-sum via ones-MFMA
#pragma unroll
    for (int kk = 0; kk < 2; ++kk) {
      short8 pa[2], vbf[4];
#pragma unroll
      for (int rt = 0; rt < 2; ++rt)
        pa[rt] =
            *(const short8*)&Ps[w][rt * 16 + (l & 15)][kk * 32 + (l >> 4) * 8];
#pragma unroll
      for (int dt = 0; dt < 4; ++dt) {
        int R = dt * 16 + (l & 15);
        int ch = ((kk << 2) + (l >> 4)) ^ (l & 7);
        vbf[dt] =
            *(const short8*)((const char*)&Vb[cur][0][0] + R * 128 + ch * 16);
      }
#pragma unroll
      for (int rt = 0; rt < 2; ++rt) {
        l_acc[rt] = mfma16(pa[rt], ones, l_acc[rt]);
#pragma unroll
        for (int dt = 0; dt < 4; ++dt)
          o_acc[rt][dt] = mfma16(pa[rt], vbf[dt], o_acc[rt][dt]);
      }
    }
    __syncthreads();  // drains vmcnt (prefetch done) + frees cur for rewrite
  }
#undef STAGE
#pragma unroll
  for (int rt = 0; rt < 2; ++rt)
#pragma unroll
    for (int q = 0; q < 4; ++q) {
      float inv = 1.f / l_acc[rt][q];
      int r = qb * 128 + w * 32 + rt * 16 + (l >> 4) * 4 + q;
#pragma unroll
      for (int dt = 0; dt < 4; ++dt)
        ctx[(rowbase + r) * 512 + hoff + dt * 16 + (l & 15)] =
            f2b(o_acc[rt][dt][q] * inv);
    }
}

// ---------------------------------------------------------------------------
// t[r][j] = sum_m ctx_m[r][:] . WEFFT[m][j][:]   (r = b*512+s, j = o*3+k)
// ---------------------------------------------------------------------------
__global__ __launch_bounds__(64) void t_gemm(const u16* __restrict__ ctx4,
                                             const u16* __restrict__ WEFFT,
                                             float* __restrict__ t) {
  const int l = threadIdx.x;
  const long r0 = (long)blockIdx.x * 16;
  f32x4 acc = {};
#pragma unroll
  for (int m = 0; m < 4; ++m) {
    const u16* A =
        ctx4 + (long)m * 8388608 + (r0 + (l & 15)) * 512 + (l >> 4) * 8;
    const u16* Bb = WEFFT + m * 8192 + (l & 15) * 512 + (l >> 4) * 8;
#pragma unroll
    for (int kt = 0; kt < 16; ++kt) {
      short8 af = *(const short8*)(A + kt * 32);
      short8 bf = *(const short8*)(Bb + kt * 32);
      acc = mfma16(af, bf, acc);
    }
  }
#pragma unroll
  for (int q = 0; q < 4; ++q)
    t[(r0 + (l >> 4) * 4 + q) * 16 + (l & 15)] = acc[q];
}

// ---------------------------------------------------------------------------
// c1[b][o][s] = elu(b1[o] + sum_k in-range (t[b,s+k-1,o*3+k] + bias_t[o*3+k]))
// ---------------------------------------------------------------------------
__global__ __launch_bounds__(256) void c1_kernel(
    const float* __restrict__ t, const float* __restrict__ bias_t,
    const float* __restrict__ b1, float* __restrict__ c1) {
  int idx = blockIdx.x * 256 + threadIdx.x;  // (b*5+o)*512+s
  int s = idx & 511;
  int rest = idx >> 9;
  int o = rest % 5, b = rest / 5;
  float a = b1[o];
  long base = (long)b * 512;
#pragma unroll
  for (int k = 0; k < 3; ++k) {
    int ss = s + k - 1;
    if (ss >= 0 && ss < 512)
      a += t[(base + ss) * 16 + o * 3 + k] + bias_t[o * 3 + k];
  }
  c1[idx] = eluf(a);
}

// ---------------------------------------------------------------------------
// conv2 + elu + pairwise max-pool -> flat (32 x 512)
// ---------------------------------------------------------------------------
__global__ __launch_bounds__(256) void conv2pool(const float* __restrict__ c1,
                                                 const float* __restrict__ w2,
                                                 const float* __restrict__ b2,
                                                 float* __restrict__ flat) {
  int idx = blockIdx.x * 256 + threadIdx.x;  // 0..16383
  int b = idx >> 9, r = idx & 511, o = r >> 8, sp = r & 255;
  float mx = -1e30f;
#pragma unroll
  for (int sd = 0; sd < 2; ++sd) {
    int s = sp * 2 + sd;
    float a = b2[o];
#pragma unroll
    for (int ic = 0; ic < 5; ++ic)
#pragma unroll
      for (int k = 0; k < 3; ++k) {
        int ss = s + k - 1;
        if (ss >= 0 && ss < 512)
          a += c1[((long)b * 5 + ic) * 512 + ss] * w2[(o * 5 + ic) * 3 + k];
      }
    mx = fmaxf(mx, eluf(a));
  }
  flat[idx] = mx;
}

// ---------------------------------------------------------------------------
// FC head + LayerNorm, one block per batch element
// ---------------------------------------------------------------------------
__global__ __launch_bounds__(256) void head_kernel(
    const float* __restrict__ flat, const float* __restrict__ w1,
    const float* __restrict__ b1, const float* __restrict__ w2,
    const float* __restrict__ b2, const float* __restrict__ w3,
    const float* __restrict__ b3, const float* __restrict__ g,
    const float* __restrict__ be, float* __restrict__ out) {
  __shared__ float xb[512], z1[256], z2[128], z3[96];
  int b = blockIdx.x, t = threadIdx.x;
  xb[t] = flat[b * 512 + t];
  xb[t + 256] = flat[b * 512 + t + 256];
  __syncthreads();
  {
    float a = b1[t];
    for (int i = 0; i < 512; ++i) a += xb[i] * w1[i * 256 + t];
    z1[t] = eluf(a);
  }
  __syncthreads();
  if (t < 128) {
    float a = b2[t];
    for (int i = 0; i < 256; ++i) a += z1[i] * w2[i * 128 + t];
    z2[t] = eluf(a);
  }
  __syncthreads();
  if (t < 96) {
    float a = b3[t];
    for (int i = 0; i < 128; ++i) a += z2[i] * w3[i * 96 + t];
    z3[t] = a;
  }
  __syncthreads();
  if (t < 96) {
    float mu = 0.f;
    for (int j = 0; j < 96; ++j) mu += z3[j];
    mu *= (1.f / 96.f);
    float sq = 0.f;
    for (int j = 0; j < 96; ++j) {
      float d = z3[j] - mu;
      sq += d * d;
    }
    float var = sq * (1.f / 96.f);
    out[b * 96 + t] = (z3[t] - mu) / sqrtf(var + 1e-5f) * g[t] + be[t];
  }
}

// ---------------------------------------------------------------------------
extern "C" void kernel_launch(void* const* d_in, const int* in_sizes, int n_in,
                              void* d_out, int out_size, void* d_ws,
                              size_t ws_size, hipStream_t stream) {
  (void)in_sizes; (void)n_in; (void)out_size;
  const float* x    = (const float*)d_in[0];
  const float* embW = (const float*)d_in[1];
  const float* embB = (const float*)d_in[2];
  const float* Wq   = (const float*)d_in[3];
  const float* bq   = (const float*)d_in[4];
  const float* Wk   = (const float*)d_in[5];
  const float* bk   = (const float*)d_in[6];
  const float* Wv   = (const float*)d_in[7];
  const float* bv   = (const float*)d_in[8];
  const float* Wo   = (const float*)d_in[9];
  const float* bo   = (const float*)d_in[10];
  const float* c1w  = (const float*)d_in[11];
  const float* c1b  = (const float*)d_in[12];
  const float* c2w  = (const float*)d_in[13];
  const float* c2b  = (const float*)d_in[14];
  const float* f1w  = (const float*)d_in[15];
  const float* f1b  = (const float*)d_in[16];
  const float* f2w  = (const float*)d_in[17];
  const float* f2b_ = (const float*)d_in[18];
  const float* f3w  = (const float*)d_in[19];
  const float* f3b  = (const float*)d_in[20];
  const float* lng  = (const float*)d_in[21];
  const float* lnb  = (const float*)d_in[22];
  float* out = (float*)d_out;

  char* p = (char*)d_ws;
  const size_t NEED = 148955200;
  if (ws_size < NEED) return;
  u16*   A_pe    = (u16*)(p + 0);           //   512x512 bf16
  u16*   WTqkv   = (u16*)(p + 524288);      //  12x512x512 bf16
  float* pb_bias = (float*)(p + 6815744);   //  12x512 f32
  float* EW      = (float*)(p + 6840320);   //  12x4x512 f32
  u16*   PB      = (u16*)(p + 6938624);     //  12x512x512 bf16
  u16*   Qm      = (u16*)(p + 13230080);    //  16384x512 bf16
  u16*   Km      = (u16*)(p + 30007296);
  u16*   Vm      = (u16*)(p + 46784512);
  u16*   VTm     = (u16*)(p + 63561728);
  u16*   ctx4    = (u16*)(p + 80338944);    //  4x16384x512 bf16
  u16*   WEFFT   = (u16*)(p + 147447808);   //  4x16x512 bf16
  float* bias_t  = (float*)(p + 147513344); //  16 f32
  float* t_buf   = (float*)(p + 147513408); //  16384x16 f32
  float* c1buf   = (float*)(p + 148561984); //  32x5x512 f32
  float* flat    = (float*)(p + 148889664); //  32x512 f32

  prep_pe<<<536, 256, 0, stream>>>(embB, bq, bk, bv, A_pe, pb_bias);
  transw<<<dim3(12, 8, 8), 256, 0, stream>>>(Wq, Wk, Wv, WTqkv);
  ew_kernel<<<48, 256, 0, stream>>>(Wq, Wk, Wv, embW, EW);
  weff_kernel<<<2049, 64, 0, stream>>>(Wo, bo, c1w, WEFFT, bias_t);
  // PB[z] = (PE+emb_b) @ W_z + bias_z   (bf16 out)
  gemm_bt<true><<<dim3(4, 4, 12), 256, 0, stream>>>(
      A_pe, 0, 512, WTqkv, pb_bias, (void*)PB, 262144, 512);

  for (int m = 0; m < 4; ++m) {
    qkv_gen<<<16384, 256, 0, stream>>>(x, EW, PB, Qm, Km, Vm, m);
    vtrans<<<dim3(256, 8), 256, 0, stream>>>(Vm, VTm);
    attn_kernel<<<dim3(256, 4), 256, 0, stream>>>(
        Qm, Km, VTm, ctx4 + (long)m * 8388608);
  }

  t_gemm<<<1024, 64, 0, stream>>>(ctx4, WEFFT, t_buf);
  c1_kernel<<<320, 256, 0, stream>>>(t_buf, bias_t, c1b, c1buf);
  conv2pool<<<64, 256, 0, stream>>>(c1buf, c2w, c2b, flat);
  head_kernel<<<32, 256, 0, stream>>>(flat, f1w, f1b, f2w, f2b_, f3w, f3b,
                                      lng, lnb, out);
}